// Round 7
// baseline (174.704 us; speedup 1.0000x reference)
//
#include <hip/hip_runtime.h>

#define B 2
#define S 2048
#define D 512
#define H 8
#define KD 64

typedef __bf16 bf16_t;
typedef __bf16 bf16x8 __attribute__((ext_vector_type(8)));
typedef __bf16 bf16x4 __attribute__((ext_vector_type(4)));
typedef float f32x4 __attribute__((ext_vector_type(4)));

#define QSCALE 0.1803368801111204f   /* 0.125 * log2(e): exp2-domain softmax */

__device__ __forceinline__ void async_copy16(const void* g, void* l) {
    __builtin_amdgcn_global_load_lds(
        (const __attribute__((address_space(1))) void*)g,
        (__attribute__((address_space(3))) void*)l, 16, 0, 0);
}

// ---------------------------------------------------------------------------
// Kernel 0: weight prep (transpose + f32->bf16, once per launch):
//   Wt{q,k,v}[h][col(64)][d(512)]  <-  W*[h][d][col]   (== [n=512][k=512])
//   WoT[n(512)][k(512)]            <-  Wo[k][n]
// ---------------------------------------------------------------------------
__global__ __launch_bounds__(256) void prep_kernel(
    const float* __restrict__ Wq, const float* __restrict__ Wk,
    const float* __restrict__ Wv, const float* __restrict__ Wo,
    bf16_t* __restrict__ Wtq, bf16_t* __restrict__ Wtk,
    bf16_t* __restrict__ Wtv, bf16_t* __restrict__ WoT)
{
    __shared__ bf16_t tl[64][72];
    const int blk = blockIdx.x, t = threadIdx.x;

    const float* src; bf16_t* dstbase;
    int ld, r0, c0;
    if (blk < 192) {                       // Wq/Wk/Wv
        const int mat = blk >> 6, h = (blk & 63) >> 3, dt = blk & 7;
        const float* W = (mat == 0) ? Wq : (mat == 1) ? Wk : Wv;
        bf16_t* Wt = (mat == 0) ? Wtq : (mat == 1) ? Wtk : Wtv;
        src = W + (size_t)h * D * KD; dstbase = Wt + (size_t)h * KD * D;
        ld = KD; r0 = dt * 64; c0 = 0;
    } else {                               // Wo
        const int kt = (blk - 192) >> 3, nt = (blk - 192) & 7;
        src = Wo; dstbase = WoT;
        ld = D; r0 = kt * 64; c0 = nt * 64;
    }

    { // phase 1: read f32 rows, convert, store to LDS [row][col]
        const int r = t >> 2, cq = (t & 3) * 16;
        const float* sp = src + (size_t)(r0 + r) * ld + c0 + cq;
#pragma unroll
        for (int q = 0; q < 4; ++q) {
            const float4 f = *reinterpret_cast<const float4*>(sp + q * 4);
            tl[r][cq + q * 4 + 0] = (bf16_t)f.x; tl[r][cq + q * 4 + 1] = (bf16_t)f.y;
            tl[r][cq + q * 4 + 2] = (bf16_t)f.z; tl[r][cq + q * 4 + 3] = (bf16_t)f.w;
        }
    }
    __syncthreads();
    { // phase 2: gather transposed, 16B stores
        const int cc = t >> 2, rq = (t & 3) * 16;
        bf16x8 o0, o1;
#pragma unroll
        for (int j = 0; j < 8; ++j) { o0[j] = tl[rq + j][cc]; o1[j] = tl[rq + 8 + j][cc]; }
        bf16_t* dp = dstbase + (size_t)(c0 + cc) * 512 + r0 + rq;
        *reinterpret_cast<bf16x8*>(dp) = o0;
        *reinterpret_cast<bf16x8*>(dp + 8) = o1;
    }
}

// ---------------------------------------------------------------------------
// Kernel 1: fused QKV projection — full-width waves, X read ONCE.
// grid = (128, 3), 128 thr (2 waves). Wave owns 16 rows x ALL 512 cols:
// A-tile (16x512) held in registers (16 bf16x8), B streamed from the
// L2-resident Wt (=[n][k] bf16), ct swept 0..31 with 2 interleaved acc
// chains. No LDS, no X re-fetch across heads.
// ---------------------------------------------------------------------------
__global__ __launch_bounds__(128) void qkv_kernel(
    const float* __restrict__ q_in, const float* __restrict__ k_in, const float* __restrict__ v_in,
    const bf16_t* __restrict__ Wtq, const bf16_t* __restrict__ Wtk, const bf16_t* __restrict__ Wtv,
    const float* __restrict__ bq, const float* __restrict__ bk, const float* __restrict__ bv,
    bf16_t* __restrict__ Qo, bf16_t* __restrict__ Ko, bf16_t* __restrict__ VTo)
{
    const int mat = blockIdx.y;
    const float* Xp   = (mat == 0) ? q_in : (mat == 1) ? k_in : v_in;
    const bf16_t* Wt  = (mat == 0) ? Wtq  : (mat == 1) ? Wtk  : Wtv;
    const float* bias = (mat == 0) ? bq   : (mat == 1) ? bk   : bv;
    const float scale = (mat == 0) ? QSCALE : 1.0f;

    const int tid = threadIdx.x, wave = tid >> 6, lane = tid & 63;
    const int g = lane >> 4, c = lane & 15;

    const int row0 = (blockIdx.x * 2 + wave) * 16;   // [0, 4096)
    const int b = row0 >> 11, s0 = row0 & 2047;

    // ---- A-tile into registers: af[ks] = X[row0+c][ks*32 + g*8 ..+7] (bf16)
    bf16x8 af[16];
    {
        const float* xrow = Xp + ((size_t)row0 + c) * D;
#pragma unroll
        for (int ks = 0; ks < 16; ++ks) {
            const float4 f0 = *reinterpret_cast<const float4*>(xrow + ks * 32 + g * 8);
            const float4 f1 = *reinterpret_cast<const float4*>(xrow + ks * 32 + g * 8 + 4);
            bf16x8 a;
            a[0] = (bf16_t)f0.x; a[1] = (bf16_t)f0.y; a[2] = (bf16_t)f0.z; a[3] = (bf16_t)f0.w;
            a[4] = (bf16_t)f1.x; a[5] = (bf16_t)f1.y; a[6] = (bf16_t)f1.z; a[7] = (bf16_t)f1.w;
            af[ks] = a;
        }
    }

    const f32x4 zero = {0.f, 0.f, 0.f, 0.f};

#pragma unroll 2
    for (int ct2 = 0; ct2 < 16; ++ct2) {
        const int ct0 = ct2 * 2, ct1 = ct2 * 2 + 1;
        const bf16_t* b0 = Wt + (size_t)(ct0 * 16 + c) * 512 + g * 8;
        const bf16_t* b1 = Wt + (size_t)(ct1 * 16 + c) * 512 + g * 8;
        f32x4 acc0 = zero, acc1 = zero;
#pragma unroll
        for (int ks = 0; ks < 16; ++ks) {
            const bf16x8 w0 = *reinterpret_cast<const bf16x8*>(b0 + ks * 32);
            const bf16x8 w1 = *reinterpret_cast<const bf16x8*>(b1 + ks * 32);
            acc0 = __builtin_amdgcn_mfma_f32_16x16x32_bf16(af[ks], w0, acc0, 0, 0, 0);
            acc1 = __builtin_amdgcn_mfma_f32_16x16x32_bf16(af[ks], w1, acc1, 0, 0, 0);
        }
        // ---- epilogue for ct0, ct1 (all lanes of a ct are in one head)
#pragma unroll 2
        for (int e = 0; e < 2; ++e) {
            const int ct = e ? ct1 : ct0;
            const f32x4 a4 = e ? acc1 : acc0;
            const int n = ct * 16 + c;
            const int h = ct >> 2, col = (ct & 3) * 16 + c;
            const int bh = b * H + h;
            const float bval = bias[n];
            if (mat < 2) {
                bf16_t* outp = (mat == 0 ? Qo : Ko);
#pragma unroll
                for (int i = 0; i < 4; ++i)
                    outp[((size_t)bh * S + s0 + g * 4 + i) * KD + col] =
                        (bf16_t)((a4[i] + bval) * scale);
            } else {
                bf16x4 o;
#pragma unroll
                for (int i = 0; i < 4; ++i) o[i] = (bf16_t)(a4[i] + bval);
                *reinterpret_cast<bf16x4*>(VTo + ((size_t)bh * KD + col) * S + s0 + 4 * g) = o;
            }
        }
    }
}

// ---------------------------------------------------------------------------
// Kernel 2: flash attention, KV-split over grid (flash-decode).
// 256*SPLIT blocks (XCD-pinned per bh), 512 thr (8 waves x 16 q-rows).
// ---------------------------------------------------------------------------
template <int SPLIT>
__global__ __launch_bounds__(512) void attn_kernel(
    const bf16_t* __restrict__ Q,   // [BH, S, 64] (pre-scaled)
    const bf16_t* __restrict__ Km,  // [BH, S, 64]
    const bf16_t* __restrict__ VT,  // [BH, 64, S]
    bf16_t* __restrict__ CTX,       // [B*S, 512] bf16 (SPLIT==1)
    float* __restrict__ Opart,      // [SPLIT][16][2048][64] f32 (SPLIT>1)
    float* __restrict__ ML)         // [SPLIT][16][2048][2]  f32 (SPLIT>1)
{
    __shared__ char kv_lds[2][16384];   // per buf: K [64][128B] | V [64][128B]

    const int hw = blockIdx.x;                       // 256*SPLIT blocks
    const int xcd = hw & 7;
    const int idx = hw >> 3;                         // 0 .. 32*SPLIT-1
    const int bh = xcd * 2 + (idx >= 16 * SPLIT ? 1 : 0);
    const int r2 = idx & (16 * SPLIT - 1);
    const int chunk = r2 >> 4;
    const int stile = r2 & 15;
    const int b = bh >> 3, h = bh & (H - 1);

    const int tid = threadIdx.x, wave = tid >> 6, lane = tid & 63;
    const int g = lane >> 4, c = lane & 15;
    const int q0 = stile * 128 + wave * 16;
    const int kvbeg = chunk * (S / SPLIT);
    const int NT = (S / SPLIT) / 64;

    const bf16_t* kg = Km + (size_t)bh * S * KD;
    const bf16_t* vg = VT + (size_t)bh * KD * S;

    const bf16_t* qp = Q + ((size_t)bh * S + q0 + c) * KD;
    const bf16x8 qlo = *reinterpret_cast<const bf16x8*>(qp + g * 8);
    const bf16x8 qhi = *reinterpret_cast<const bf16x8*>(qp + 32 + g * 8);

    int koff[4][2], voff[4][2];
#pragma unroll
    for (int tt = 0; tt < 4; ++tt) {
        const int row = 8 * (c >> 2) + (c & 3) + 4 * (tt & 1) + 32 * (tt >> 1);
        const int ys = (row & 7) ^ (((row >> 3) & 1) << 2);
        koff[tt][0] = row * 128 + ((g * 16) ^ (ys << 4));
        koff[tt][1] = row * 128 + ((64 + g * 16) ^ (ys << 4));
    }
#pragma unroll
    for (int ct = 0; ct < 4; ++ct) {
        const int row = ct * 16 + c;
        const int ys = (row & 7) ^ (((row >> 3) & 1) << 2);
        voff[ct][0] = 8192 + row * 128 + ((g * 16) ^ (ys << 4));
        voff[ct][1] = 8192 + row * 128 + ((64 + g * 16) ^ (ys << 4));
    }

    const int srow = lane >> 3, sslot = lane & 7;
    const int kwv = wave & 3;
    const int krow0a = kwv * 16, krow0b = kwv * 16 + 8;
    const int rowa = krow0a + srow, rowb = krow0b + srow;
    const int ysa = (rowa & 7) ^ (((rowa >> 3) & 1) << 2);
    const int ysb = (rowb & 7) ^ (((rowb >> 3) & 1) << 2);
    const int ssa = sslot ^ ysa, ssb = sslot ^ ysb;

    const f32x4 zero = {0.f, 0.f, 0.f, 0.f};
    f32x4 acc[4] = {zero, zero, zero, zero};
    float m_run = -1e30f, l_run = 0.f;

#define STAGE(bufidx, kv0)                                                        \
    do {                                                                          \
        char* bp = kv_lds[0] + (bufidx) * 16384;                                  \
        if (wave < 4) {                                                           \
            async_copy16(kg + (size_t)((kv0) + rowa) * KD + ssa * 8, bp + krow0a * 128); \
            async_copy16(kg + (size_t)((kv0) + rowb) * KD + ssb * 8, bp + krow0b * 128); \
        } else {                                                                  \
            async_copy16(vg + (size_t)rowa * S + (kv0) + ssa * 8, bp + 8192 + krow0a * 128); \
            async_copy16(vg + (size_t)rowb * S + (kv0) + ssb * 8, bp + 8192 + krow0b * 128); \
        }                                                                         \
    } while (0)

    STAGE(0, kvbeg);
    __syncthreads();

    int buf = 0;
    for (int t = 0; t < NT; ++t) {
        if (t < NT - 1) STAGE(buf ^ 1, kvbeg + (t + 1) * 64);
        const char* kb = kv_lds[0] + buf * 16384;

        // ---- QK^T (swapped)
        f32x4 sc[4];
        __builtin_amdgcn_s_setprio(1);
#pragma unroll
        for (int tt = 0; tt < 4; ++tt) {
            const bf16x8 k0f = *reinterpret_cast<const bf16x8*>(kb + koff[tt][0]);
            const bf16x8 k1f = *reinterpret_cast<const bf16x8*>(kb + koff[tt][1]);
            f32x4 z = zero;
            z = __builtin_amdgcn_mfma_f32_16x16x32_bf16(k0f, qlo, z, 0, 0, 0);
            sc[tt] = __builtin_amdgcn_mfma_f32_16x16x32_bf16(k1f, qhi, z, 0, 0, 0);
        }
        __builtin_amdgcn_s_setprio(0);

        // ---- softmax (exp2 domain, deferred max)
        const float a0 = fmaxf(fmaxf(sc[0][0], sc[0][1]), fmaxf(sc[0][2], sc[0][3]));
        const float a1 = fmaxf(fmaxf(sc[1][0], sc[1][1]), fmaxf(sc[1][2], sc[1][3]));
        const float a2 = fmaxf(fmaxf(sc[2][0], sc[2][1]), fmaxf(sc[2][2], sc[2][3]));
        const float a3 = fmaxf(fmaxf(sc[3][0], sc[3][1]), fmaxf(sc[3][2], sc[3][3]));
        float pm = fmaxf(fmaxf(a0, a1), fmaxf(a2, a3));
        if (!__all(pm <= m_run + 8.0f)) {
            pm = fmaxf(pm, __shfl_xor(pm, 16));
            pm = fmaxf(pm, __shfl_xor(pm, 32));
            const float mn = fmaxf(m_run, pm);
            const float fs = exp2f(m_run - mn);
            m_run = mn;
            l_run *= fs;
#pragma unroll
            for (int ct = 0; ct < 4; ++ct) acc[ct] = acc[ct] * fs;
        }

        bf16x8 f0, f1;
        float ls = 0.f;
#pragma unroll
        for (int i = 0; i < 4; ++i) {
            const float p0 = exp2f(sc[0][i] - m_run);
            const float p1 = exp2f(sc[1][i] - m_run);
            const float p2 = exp2f(sc[2][i] - m_run);
            const float p3 = exp2f(sc[3][i] - m_run);
            f0[i] = (bf16_t)p0; f0[4 + i] = (bf16_t)p1;
            f1[i] = (bf16_t)p2; f1[4 + i] = (bf16_t)p3;
            ls += (p0 + p1) + (p2 + p3);
        }
        l_run += ls;

        // ---- PV
        __builtin_amdgcn_s_setprio(1);
#pragma unroll
        for (int ct = 0; ct < 4; ++ct) {
            const bf16x8 v0f = *reinterpret_cast<const bf16x8*>(kb + voff[ct][0]);
            const bf16x8 v1f = *reinterpret_cast<const bf16x8*>(kb + voff[ct][1]);
            acc[ct] = __builtin_amdgcn_mfma_f32_16x16x32_bf16(v0f, f0, acc[ct], 0, 0, 0);
            acc[ct] = __builtin_amdgcn_mfma_f32_16x16x32_bf16(v1f, f1, acc[ct], 0, 0, 0);
        }
        __builtin_amdgcn_s_setprio(0);

        __syncthreads();
        buf ^= 1;
    }
#undef STAGE

    l_run += __shfl_xor(l_run, 16);
    l_run += __shfl_xor(l_run, 32);

    if constexpr (SPLIT == 1) {
        const float inv = 1.0f / l_run;
        bf16_t* crow = CTX + ((size_t)b * S + q0 + c) * 512 + h * 64;
#pragma unroll
        for (int ct = 0; ct < 4; ++ct) {
            bf16x4 o;
#pragma unroll
            for (int i = 0; i < 4; ++i) o[i] = (bf16_t)(acc[ct][i] * inv);
            *reinterpret_cast<bf16x4*>(crow + ct * 16 + 4 * g) = o;
        }
    } else {
        const size_t prow = (size_t)(chunk * 16 + bh) * 2048 + q0 + c;
        float* orow = Opart + prow * 64;
#pragma unroll
        for (int ct = 0; ct < 4; ++ct) {
            f32x4 o = acc[ct];
            *reinterpret_cast<f32x4*>(orow + ct * 16 + 4 * g) = o;
        }
        if (g == 0) {
            float2 ml; ml.x = m_run; ml.y = l_run;
            *reinterpret_cast<float2*>(ML + prow * 2) = ml;
        }
    }
}

// ---------------------------------------------------------------------------
// Kernel 2b: combine KV-split partials -> bf16 ctx. 2048 blocks x 256.
// ---------------------------------------------------------------------------
template <int SPLIT>
__global__ __launch_bounds__(256) void combine_kernel(
    const float* __restrict__ Opart, const float* __restrict__ ML,
    bf16_t* __restrict__ CTX)
{
    const int gid = blockIdx.x * 256 + threadIdx.x;
    const int d4 = gid & 15, rowh = gid >> 4;       // rowh = bh*2048 + s
    const int bh = rowh >> 11, s = rowh & 2047;
    const int b = bh >> 3, h = bh & (H - 1);

    float m[SPLIT], l[SPLIT], M = -1e30f;
#pragma unroll
    for (int i = 0; i < SPLIT; ++i) {
        const float2 v = *reinterpret_cast<const float2*>(
            ML + ((size_t)(i * 16 + bh) * 2048 + s) * 2);
        m[i] = v.x; l[i] = v.y;
        M = fmaxf(M, m[i]);
    }
    f32x4 o = {0.f, 0.f, 0.f, 0.f};
    float wsum = 0.f;
#pragma unroll
    for (int i = 0; i < SPLIT; ++i) {
        const float w = exp2f(m[i] - M);
        wsum += w * l[i];
        const f32x4 ov = *reinterpret_cast<const f32x4*>(
            Opart + ((size_t)(i * 16 + bh) * 2048 + s) * 64 + d4 * 4);
        o += ov * w;
    }
    const float inv = 1.0f / wsum;
    bf16x4 r;
#pragma unroll
    for (int i = 0; i < 4; ++i) r[i] = (bf16_t)(o[i] * inv);
    *reinterpret_cast<bf16x4*>(CTX + ((size_t)b * S + s) * 512 + h * 64 + d4 * 4) = r;
}

// ---------------------------------------------------------------------------
// Kernel 3: output projection — same full-width reg-A structure as qkv.
// grid = 128 blocks x 128 thr (2 waves x 16 rows x 512 cols). CTX read ONCE.
// ---------------------------------------------------------------------------
__global__ __launch_bounds__(128) void out_proj_kernel(
    const bf16_t* __restrict__ CTX,
    const bf16_t* __restrict__ WoT,   // [512 n][512 k]
    const float* __restrict__ bo,
    float* __restrict__ out)
{
    const int tid = threadIdx.x, wave = tid >> 6, lane = tid & 63;
    const int g = lane >> 4, c = lane & 15;
    const int row0 = (blockIdx.x * 2 + wave) * 16;

    // A-tile into registers
    bf16x8 af[16];
    {
        const bf16_t* arow = CTX + (size_t)(row0 + c) * 512;
#pragma unroll
        for (int ks = 0; ks < 16; ++ks)
            af[ks] = *reinterpret_cast<const bf16x8*>(arow + ks * 32 + g * 8);
    }

    const f32x4 zero = {0.f, 0.f, 0.f, 0.f};

#pragma unroll 2
    for (int ct2 = 0; ct2 < 16; ++ct2) {
        const int ct0 = ct2 * 2, ct1 = ct2 * 2 + 1;
        const bf16_t* b0 = WoT + (size_t)(ct0 * 16 + c) * 512 + g * 8;
        const bf16_t* b1 = WoT + (size_t)(ct1 * 16 + c) * 512 + g * 8;
        f32x4 acc0 = zero, acc1 = zero;
#pragma unroll
        for (int ks = 0; ks < 16; ++ks) {
            const bf16x8 w0 = *reinterpret_cast<const bf16x8*>(b0 + ks * 32);
            const bf16x8 w1 = *reinterpret_cast<const bf16x8*>(b1 + ks * 32);
            acc0 = __builtin_amdgcn_mfma_f32_16x16x32_bf16(af[ks], w0, acc0, 0, 0, 0);
            acc1 = __builtin_amdgcn_mfma_f32_16x16x32_bf16(af[ks], w1, acc1, 0, 0, 0);
        }
#pragma unroll 2
        for (int e = 0; e < 2; ++e) {
            const int n = (e ? ct1 : ct0) * 16 + c;
            const f32x4 a4 = e ? acc1 : acc0;
            const float bval = bo[n];
#pragma unroll
            for (int i = 0; i < 4; ++i)
                out[(size_t)(row0 + 4 * g + i) * 512 + n] = a4[i] + bval;
        }
    }
}

// ---------------------------------------------------------------------------
extern "C" void kernel_launch(void* const* d_in, const int* in_sizes, int n_in,
                              void* d_out, int out_size, void* d_ws, size_t ws_size,
                              hipStream_t stream) {
    const float* query = (const float*)d_in[0];
    const float* key_  = (const float*)d_in[1];
    const float* value = (const float*)d_in[2];
    const float* Wq = (const float*)d_in[3];
    const float* bq = (const float*)d_in[4];
    const float* Wk = (const float*)d_in[5];
    const float* bk = (const float*)d_in[6];
    const float* Wv = (const float*)d_in[7];
    const float* bv = (const float*)d_in[8];
    const float* Wo = (const float*)d_in[9];
    const float* bo = (const float*)d_in[10];

    char* wsb = (char*)d_ws;
    bf16_t* Qw   = (bf16_t*)(wsb);                       // 4 MB
    bf16_t* Kw   = (bf16_t*)(wsb + (4u  << 20));         // 4 MB
    bf16_t* VTw  = (bf16_t*)(wsb + (8u  << 20));         // 4 MB
    bf16_t* CTXb = (bf16_t*)(wsb + (12u << 20));         // 4 MB
    bf16_t* Wtq  = (bf16_t*)(wsb + (16u << 20));         // 512 KB
    bf16_t* Wtk  = Wtq + 8 * 64 * 512;
    bf16_t* Wtv  = Wtk + 8 * 64 * 512;
    bf16_t* WoTw = (bf16_t*)(wsb + (18u << 20));         // 512 KB
    float*  Opart = (float*)(wsb + (20u << 20));         // SPLIT x 8 MB

    const int SPLIT = (ws_size >= (56ull << 20)) ? 4
                    : (ws_size >= (40ull << 20)) ? 2 : 1;

    prep_kernel<<<256, 256, 0, stream>>>(Wq, Wk, Wv, Wo, Wtq, Wtk, Wtv, WoTw);
    qkv_kernel<<<dim3(128, 3), 128, 0, stream>>>(query, key_, value,
                                                 Wtq, Wtk, Wtv, bq, bk, bv,
                                                 Qw, Kw, VTw);

    if (SPLIT == 4) {
        float* MLp = Opart + 4ull * 16 * 2048 * 64;
        attn_kernel<4><<<1024, 512, 0, stream>>>(Qw, Kw, VTw, CTXb, Opart, MLp);
        combine_kernel<4><<<2048, 256, 0, stream>>>(Opart, MLp, CTXb);
    } else if (SPLIT == 2) {
        float* MLp = Opart + 2ull * 16 * 2048 * 64;
        attn_kernel<2><<<512, 512, 0, stream>>>(Qw, Kw, VTw, CTXb, Opart, MLp);
        combine_kernel<2><<<2048, 256, 0, stream>>>(Opart, MLp, CTXb);
    } else {
        attn_kernel<1><<<256, 512, 0, stream>>>(Qw, Kw, VTw, CTXb, nullptr, nullptr);
    }

    out_proj_kernel<<<128, 128, 0, stream>>>(CTXb, WoTw, bo, (float*)d_out);
}

// Round 8
// 139.009 us; speedup vs baseline: 1.2568x; 1.2568x over previous
//
#include <hip/hip_runtime.h>

#define B 2
#define S 2048
#define D 512
#define H 8
#define KD 64

typedef __bf16 bf16_t;
typedef __bf16 bf16x8 __attribute__((ext_vector_type(8)));
typedef __bf16 bf16x4 __attribute__((ext_vector_type(4)));
typedef float f32x4 __attribute__((ext_vector_type(4)));

#define QSCALE 0.1803368801111204f   /* 0.125 * log2(e): exp2-domain softmax */

__device__ __forceinline__ void async_copy16(const void* g, void* l) {
    __builtin_amdgcn_global_load_lds(
        (const __attribute__((address_space(1))) void*)g,
        (__attribute__((address_space(3))) void*)l, 16, 0, 0);
}

// ---------------------------------------------------------------------------
// Kernel 0: weight prep (transpose + f32->bf16, once per launch):
//   Wt{q,k,v}[h][col(64)][d(512)]  <-  W*[h][d][col]
//   WoT[n(512)][k(512)]            <-  Wo[k][n]
// ---------------------------------------------------------------------------
__global__ __launch_bounds__(256) void prep_kernel(
    const float* __restrict__ Wq, const float* __restrict__ Wk,
    const float* __restrict__ Wv, const float* __restrict__ Wo,
    bf16_t* __restrict__ Wtq, bf16_t* __restrict__ Wtk,
    bf16_t* __restrict__ Wtv, bf16_t* __restrict__ WoT)
{
    __shared__ bf16_t tl[64][72];
    const int blk = blockIdx.x, t = threadIdx.x;

    const float* src; bf16_t* dstbase;
    int ld, r0, c0;
    if (blk < 192) {                       // Wq/Wk/Wv
        const int mat = blk >> 6, h = (blk & 63) >> 3, dt = blk & 7;
        const float* W = (mat == 0) ? Wq : (mat == 1) ? Wk : Wv;
        bf16_t* Wt = (mat == 0) ? Wtq : (mat == 1) ? Wtk : Wtv;
        src = W + (size_t)h * D * KD; dstbase = Wt + (size_t)h * KD * D;
        ld = KD; r0 = dt * 64; c0 = 0;
    } else {                               // Wo
        const int kt = (blk - 192) >> 3, nt = (blk - 192) & 7;
        src = Wo; dstbase = WoT;
        ld = D; r0 = kt * 64; c0 = nt * 64;
    }

    { // phase 1: read f32 rows, convert, store to LDS [row][col]
        const int r = t >> 2, cq = (t & 3) * 16;
        const float* sp = src + (size_t)(r0 + r) * ld + c0 + cq;
#pragma unroll
        for (int q = 0; q < 4; ++q) {
            const float4 f = *reinterpret_cast<const float4*>(sp + q * 4);
            tl[r][cq + q * 4 + 0] = (bf16_t)f.x; tl[r][cq + q * 4 + 1] = (bf16_t)f.y;
            tl[r][cq + q * 4 + 2] = (bf16_t)f.z; tl[r][cq + q * 4 + 3] = (bf16_t)f.w;
        }
    }
    __syncthreads();
    { // phase 2: gather transposed, 16B stores
        const int cc = t >> 2, rq = (t & 3) * 16;
        bf16x8 o0, o1;
#pragma unroll
        for (int j = 0; j < 8; ++j) { o0[j] = tl[rq + j][cc]; o1[j] = tl[rq + 8 + j][cc]; }
        bf16_t* dp = dstbase + (size_t)(c0 + cc) * 512 + r0 + rq;
        *reinterpret_cast<bf16x8*>(dp) = o0;
        *reinterpret_cast<bf16x8*>(dp + 8) = o1;
    }
}

// ---------------------------------------------------------------------------
// Kernel 1: fused QKV projection — LDS-free, XCD-local A-panel reuse.
// grid = (512, 3): mtile = idx & 63 (low bits!), h = idx >> 6, so the 8
// head-blocks sharing an X row-panel all land on XCD = mtile%8 and the
// panel is fetched into that L2 ONCE. 256 thr (4 waves x 16 rows).
// B-frags stream from prepped Wt[h] (bf16, L2-resident).
// ---------------------------------------------------------------------------
__global__ __launch_bounds__(256) void qkv_kernel(
    const float* __restrict__ q_in, const float* __restrict__ k_in, const float* __restrict__ v_in,
    const bf16_t* __restrict__ Wtq, const bf16_t* __restrict__ Wtk, const bf16_t* __restrict__ Wtv,
    const float* __restrict__ bq, const float* __restrict__ bk, const float* __restrict__ bv,
    bf16_t* __restrict__ Qo, bf16_t* __restrict__ Ko, bf16_t* __restrict__ VTo)
{
    const int mat = blockIdx.y;
    const float* Xp     = (mat == 0) ? q_in : (mat == 1) ? k_in : v_in;
    const bf16_t* Wt    = (mat == 0) ? Wtq  : (mat == 1) ? Wtk  : Wtv;
    const float* bias   = (mat == 0) ? bq   : (mat == 1) ? bk   : bv;
    const float scale   = (mat == 0) ? QSCALE : 1.0f;

    const int mtile = blockIdx.x & 63;          // low bits -> XCD = mtile%8
    const int h     = blockIdx.x >> 6;

    const int tid = threadIdx.x, wave = tid >> 6, lane = tid & 63;
    const int g = lane >> 4, c = lane & 15;

    const int row0 = mtile * 64 + wave * 16;    // global row in [0, 4096)
    const int b = row0 >> 11;                   // 64-row tiles never cross b
    const int s0 = row0 & 2047;
    const int bh = b * H + h;

    const bf16_t* wbase = Wt + (size_t)h * (KD * 512);
    const float* xrow = Xp + ((size_t)row0 + c) * D;

    const f32x4 zero = {0.f, 0.f, 0.f, 0.f};
    f32x4 acc[4] = {zero, zero, zero, zero};

    for (int k0 = 0; k0 < D; k0 += 32) {
        bf16x8 a;
        const float4 f0 = *reinterpret_cast<const float4*>(xrow + k0 + g * 8);
        const float4 f1 = *reinterpret_cast<const float4*>(xrow + k0 + g * 8 + 4);
        a[0] = (bf16_t)f0.x; a[1] = (bf16_t)f0.y; a[2] = (bf16_t)f0.z; a[3] = (bf16_t)f0.w;
        a[4] = (bf16_t)f1.x; a[5] = (bf16_t)f1.y; a[6] = (bf16_t)f1.z; a[7] = (bf16_t)f1.w;
#pragma unroll
        for (int ct = 0; ct < 4; ++ct) {
            const bf16x8 wf = *reinterpret_cast<const bf16x8*>(
                wbase + (size_t)(ct * 16 + c) * 512 + k0 + g * 8);
            acc[ct] = __builtin_amdgcn_mfma_f32_16x16x32_bf16(a, wf, acc[ct], 0, 0, 0);
        }
    }

#pragma unroll
    for (int ct = 0; ct < 4; ++ct) {
        const int col = ct * 16 + c;
        const float bval = bias[h * KD + col];
        if (mat < 2) {
            bf16_t* outp = (mat == 0 ? Qo : Ko);
#pragma unroll
            for (int i = 0; i < 4; ++i) {
                const int s = s0 + g * 4 + i;
                outp[((size_t)bh * S + s) * KD + col] = (bf16_t)((acc[ct][i] + bval) * scale);
            }
        } else {
            bf16x4 o;
#pragma unroll
            for (int i = 0; i < 4; ++i) o[i] = (bf16_t)(acc[ct][i] + bval);
            *reinterpret_cast<bf16x4*>(VTo + ((size_t)bh * KD + col) * S + s0 + 4 * g) = o;
        }
    }
}

// ---------------------------------------------------------------------------
// Kernel 2: flash attention, KV-split over grid (flash-decode).
// 256*SPLIT blocks (XCD-pinned per bh), 512 thr (8 waves x 16 q-rows).
// ---------------------------------------------------------------------------
template <int SPLIT>
__global__ __launch_bounds__(512) void attn_kernel(
    const bf16_t* __restrict__ Q,   // [BH, S, 64] (pre-scaled)
    const bf16_t* __restrict__ Km,  // [BH, S, 64]
    const bf16_t* __restrict__ VT,  // [BH, 64, S]
    bf16_t* __restrict__ CTX,       // [B*S, 512] bf16 (SPLIT==1)
    float* __restrict__ Opart,      // [SPLIT][16][2048][64] f32 (SPLIT>1)
    float* __restrict__ ML)         // [SPLIT][16][2048][2]  f32 (SPLIT>1)
{
    __shared__ char kv_lds[2][16384];   // per buf: K [64][128B] | V [64][128B]

    const int hw = blockIdx.x;                       // 256*SPLIT blocks
    const int xcd = hw & 7;
    const int idx = hw >> 3;                         // 0 .. 32*SPLIT-1
    const int bh = xcd * 2 + (idx >= 16 * SPLIT ? 1 : 0);
    const int r2 = idx & (16 * SPLIT - 1);
    const int chunk = r2 >> 4;
    const int stile = r2 & 15;
    const int b = bh >> 3, h = bh & (H - 1);

    const int tid = threadIdx.x, wave = tid >> 6, lane = tid & 63;
    const int g = lane >> 4, c = lane & 15;
    const int q0 = stile * 128 + wave * 16;
    const int kvbeg = chunk * (S / SPLIT);
    const int NT = (S / SPLIT) / 64;

    const bf16_t* kg = Km + (size_t)bh * S * KD;
    const bf16_t* vg = VT + (size_t)bh * KD * S;

    const bf16_t* qp = Q + ((size_t)bh * S + q0 + c) * KD;
    const bf16x8 qlo = *reinterpret_cast<const bf16x8*>(qp + g * 8);
    const bf16x8 qhi = *reinterpret_cast<const bf16x8*>(qp + 32 + g * 8);

    int koff[4][2], voff[4][2];
#pragma unroll
    for (int tt = 0; tt < 4; ++tt) {
        const int row = 8 * (c >> 2) + (c & 3) + 4 * (tt & 1) + 32 * (tt >> 1);
        const int ys = (row & 7) ^ (((row >> 3) & 1) << 2);
        koff[tt][0] = row * 128 + ((g * 16) ^ (ys << 4));
        koff[tt][1] = row * 128 + ((64 + g * 16) ^ (ys << 4));
    }
#pragma unroll
    for (int ct = 0; ct < 4; ++ct) {
        const int row = ct * 16 + c;
        const int ys = (row & 7) ^ (((row >> 3) & 1) << 2);
        voff[ct][0] = 8192 + row * 128 + ((g * 16) ^ (ys << 4));
        voff[ct][1] = 8192 + row * 128 + ((64 + g * 16) ^ (ys << 4));
    }

    const int srow = lane >> 3, sslot = lane & 7;
    const int kwv = wave & 3;
    const int krow0a = kwv * 16, krow0b = kwv * 16 + 8;
    const int rowa = krow0a + srow, rowb = krow0b + srow;
    const int ysa = (rowa & 7) ^ (((rowa >> 3) & 1) << 2);
    const int ysb = (rowb & 7) ^ (((rowb >> 3) & 1) << 2);
    const int ssa = sslot ^ ysa, ssb = sslot ^ ysb;

    const f32x4 zero = {0.f, 0.f, 0.f, 0.f};
    f32x4 acc[4] = {zero, zero, zero, zero};
    float m_run = -1e30f, l_run = 0.f;

#define STAGE(bufidx, kv0)                                                        \
    do {                                                                          \
        char* bp = kv_lds[0] + (bufidx) * 16384;                                  \
        if (wave < 4) {                                                           \
            async_copy16(kg + (size_t)((kv0) + rowa) * KD + ssa * 8, bp + krow0a * 128); \
            async_copy16(kg + (size_t)((kv0) + rowb) * KD + ssb * 8, bp + krow0b * 128); \
        } else {                                                                  \
            async_copy16(vg + (size_t)rowa * S + (kv0) + ssa * 8, bp + 8192 + krow0a * 128); \
            async_copy16(vg + (size_t)rowb * S + (kv0) + ssb * 8, bp + 8192 + krow0b * 128); \
        }                                                                         \
    } while (0)

    STAGE(0, kvbeg);
    __syncthreads();

    int buf = 0;
    for (int t = 0; t < NT; ++t) {
        if (t < NT - 1) STAGE(buf ^ 1, kvbeg + (t + 1) * 64);
        const char* kb = kv_lds[0] + buf * 16384;

        // ---- QK^T (swapped)
        f32x4 sc[4];
        __builtin_amdgcn_s_setprio(1);
#pragma unroll
        for (int tt = 0; tt < 4; ++tt) {
            const bf16x8 k0f = *reinterpret_cast<const bf16x8*>(kb + koff[tt][0]);
            const bf16x8 k1f = *reinterpret_cast<const bf16x8*>(kb + koff[tt][1]);
            f32x4 z = zero;
            z = __builtin_amdgcn_mfma_f32_16x16x32_bf16(k0f, qlo, z, 0, 0, 0);
            sc[tt] = __builtin_amdgcn_mfma_f32_16x16x32_bf16(k1f, qhi, z, 0, 0, 0);
        }
        __builtin_amdgcn_s_setprio(0);

        // ---- softmax (exp2 domain, deferred max)
        const float a0 = fmaxf(fmaxf(sc[0][0], sc[0][1]), fmaxf(sc[0][2], sc[0][3]));
        const float a1 = fmaxf(fmaxf(sc[1][0], sc[1][1]), fmaxf(sc[1][2], sc[1][3]));
        const float a2 = fmaxf(fmaxf(sc[2][0], sc[2][1]), fmaxf(sc[2][2], sc[2][3]));
        const float a3 = fmaxf(fmaxf(sc[3][0], sc[3][1]), fmaxf(sc[3][2], sc[3][3]));
        float pm = fmaxf(fmaxf(a0, a1), fmaxf(a2, a3));
        if (!__all(pm <= m_run + 8.0f)) {
            pm = fmaxf(pm, __shfl_xor(pm, 16));
            pm = fmaxf(pm, __shfl_xor(pm, 32));
            const float mn = fmaxf(m_run, pm);
            const float fs = exp2f(m_run - mn);
            m_run = mn;
            l_run *= fs;
#pragma unroll
            for (int ct = 0; ct < 4; ++ct) acc[ct] = acc[ct] * fs;
        }

        bf16x8 f0, f1;
        float ls = 0.f;
#pragma unroll
        for (int i = 0; i < 4; ++i) {
            const float p0 = exp2f(sc[0][i] - m_run);
            const float p1 = exp2f(sc[1][i] - m_run);
            const float p2 = exp2f(sc[2][i] - m_run);
            const float p3 = exp2f(sc[3][i] - m_run);
            f0[i] = (bf16_t)p0; f0[4 + i] = (bf16_t)p1;
            f1[i] = (bf16_t)p2; f1[4 + i] = (bf16_t)p3;
            ls += (p0 + p1) + (p2 + p3);
        }
        l_run += ls;

        // ---- PV
        __builtin_amdgcn_s_setprio(1);
#pragma unroll
        for (int ct = 0; ct < 4; ++ct) {
            const bf16x8 v0f = *reinterpret_cast<const bf16x8*>(kb + voff[ct][0]);
            const bf16x8 v1f = *reinterpret_cast<const bf16x8*>(kb + voff[ct][1]);
            acc[ct] = __builtin_amdgcn_mfma_f32_16x16x32_bf16(v0f, f0, acc[ct], 0, 0, 0);
            acc[ct] = __builtin_amdgcn_mfma_f32_16x16x32_bf16(v1f, f1, acc[ct], 0, 0, 0);
        }
        __builtin_amdgcn_s_setprio(0);

        __syncthreads();
        buf ^= 1;
    }
#undef STAGE

    l_run += __shfl_xor(l_run, 16);
    l_run += __shfl_xor(l_run, 32);

    if constexpr (SPLIT == 1) {
        const float inv = 1.0f / l_run;
        bf16_t* crow = CTX + ((size_t)b * S + q0 + c) * 512 + h * 64;
#pragma unroll
        for (int ct = 0; ct < 4; ++ct) {
            bf16x4 o;
#pragma unroll
            for (int i = 0; i < 4; ++i) o[i] = (bf16_t)(acc[ct][i] * inv);
            *reinterpret_cast<bf16x4*>(crow + ct * 16 + 4 * g) = o;
        }
    } else {
        const size_t prow = (size_t)(chunk * 16 + bh) * 2048 + q0 + c;
        float* orow = Opart + prow * 64;
#pragma unroll
        for (int ct = 0; ct < 4; ++ct) {
            f32x4 o = acc[ct];
            *reinterpret_cast<f32x4*>(orow + ct * 16 + 4 * g) = o;
        }
        if (g == 0) {
            float2 ml; ml.x = m_run; ml.y = l_run;
            *reinterpret_cast<float2*>(ML + prow * 2) = ml;
        }
    }
}

// ---------------------------------------------------------------------------
// Kernel 2b: combine KV-split partials -> bf16 ctx. 2048 blocks x 256.
// ---------------------------------------------------------------------------
template <int SPLIT>
__global__ __launch_bounds__(256) void combine_kernel(
    const float* __restrict__ Opart, const float* __restrict__ ML,
    bf16_t* __restrict__ CTX)
{
    const int gid = blockIdx.x * 256 + threadIdx.x;
    const int d4 = gid & 15, rowh = gid >> 4;       // rowh = bh*2048 + s
    const int bh = rowh >> 11, s = rowh & 2047;
    const int b = bh >> 3, h = bh & (H - 1);

    float m[SPLIT], l[SPLIT], M = -1e30f;
#pragma unroll
    for (int i = 0; i < SPLIT; ++i) {
        const float2 v = *reinterpret_cast<const float2*>(
            ML + ((size_t)(i * 16 + bh) * 2048 + s) * 2);
        m[i] = v.x; l[i] = v.y;
        M = fmaxf(M, m[i]);
    }
    f32x4 o = {0.f, 0.f, 0.f, 0.f};
    float wsum = 0.f;
#pragma unroll
    for (int i = 0; i < SPLIT; ++i) {
        const float w = exp2f(m[i] - M);
        wsum += w * l[i];
        const f32x4 ov = *reinterpret_cast<const f32x4*>(
            Opart + ((size_t)(i * 16 + bh) * 2048 + s) * 64 + d4 * 4);
        o += ov * w;
    }
    const float inv = 1.0f / wsum;
    bf16x4 r;
#pragma unroll
    for (int i = 0; i < 4; ++i) r[i] = (bf16_t)(o[i] * inv);
    *reinterpret_cast<bf16x4*>(CTX + ((size_t)b * S + s) * 512 + h * 64 + d4 * 4) = r;
}

// ---------------------------------------------------------------------------
// Kernel 3: output projection, XCD-local A-panel reuse (same mapping as qkv):
// mtile = idx & 63 (low bits), ntile = idx >> 6. 512 blocks x 256 thr.
// ---------------------------------------------------------------------------
__global__ __launch_bounds__(256) void out_proj_kernel(
    const bf16_t* __restrict__ CTX,
    const bf16_t* __restrict__ WoT,   // [512 n][512 k]
    const float* __restrict__ bo,
    float* __restrict__ out)
{
    const int mtile = blockIdx.x & 63;          // low bits -> XCD = mtile%8
    const int ntile = blockIdx.x >> 6;
    const int n0 = ntile * 64;

    const int tid = threadIdx.x, wave = tid >> 6, lane = tid & 63;
    const int g = lane >> 4, c = lane & 15;
    const int row0 = mtile * 64 + wave * 16;

    const f32x4 zero = {0.f, 0.f, 0.f, 0.f};
    f32x4 acc[4] = {zero, zero, zero, zero};

    const bf16_t* arow = CTX + (size_t)(row0 + c) * 512;
    for (int ks = 0; ks < 16; ++ks) {
        const bf16x8 a = *reinterpret_cast<const bf16x8*>(arow + ks * 32 + g * 8);
#pragma unroll
        for (int ct = 0; ct < 4; ++ct) {
            const bf16x8 wf = *reinterpret_cast<const bf16x8*>(
                WoT + (size_t)(n0 + ct * 16 + c) * 512 + ks * 32 + g * 8);
            acc[ct] = __builtin_amdgcn_mfma_f32_16x16x32_bf16(a, wf, acc[ct], 0, 0, 0);
        }
    }

#pragma unroll
    for (int ct = 0; ct < 4; ++ct) {
        const int col = n0 + ct * 16 + c;
        const float bval = bo[col];
#pragma unroll
        for (int i = 0; i < 4; ++i)
            out[(size_t)(row0 + 4 * g + i) * 512 + col] = acc[ct][i] + bval;
    }
}

// ---------------------------------------------------------------------------
extern "C" void kernel_launch(void* const* d_in, const int* in_sizes, int n_in,
                              void* d_out, int out_size, void* d_ws, size_t ws_size,
                              hipStream_t stream) {
    const float* query = (const float*)d_in[0];
    const float* key_  = (const float*)d_in[1];
    const float* value = (const float*)d_in[2];
    const float* Wq = (const float*)d_in[3];
    const float* bq = (const float*)d_in[4];
    const float* Wk = (const float*)d_in[5];
    const float* bk = (const float*)d_in[6];
    const float* Wv = (const float*)d_in[7];
    const float* bv = (const float*)d_in[8];
    const float* Wo = (const float*)d_in[9];
    const float* bo = (const float*)d_in[10];

    char* wsb = (char*)d_ws;
    bf16_t* Qw   = (bf16_t*)(wsb);                       // 4 MB
    bf16_t* Kw   = (bf16_t*)(wsb + (4u  << 20));         // 4 MB
    bf16_t* VTw  = (bf16_t*)(wsb + (8u  << 20));         // 4 MB
    bf16_t* CTXb = (bf16_t*)(wsb + (12u << 20));         // 4 MB
    bf16_t* Wtq  = (bf16_t*)(wsb + (16u << 20));         // 512 KB
    bf16_t* Wtk  = Wtq + 8 * 64 * 512;
    bf16_t* Wtv  = Wtk + 8 * 64 * 512;
    bf16_t* WoTw = (bf16_t*)(wsb + (18u << 20));         // 512 KB
    float*  Opart = (float*)(wsb + (20u << 20));         // SPLIT x 8 MB

    const int SPLIT = (ws_size >= (56ull << 20)) ? 4
                    : (ws_size >= (40ull << 20)) ? 2 : 1;

    prep_kernel<<<256, 256, 0, stream>>>(Wq, Wk, Wv, Wo, Wtq, Wtk, Wtv, WoTw);
    qkv_kernel<<<dim3(512, 3), 256, 0, stream>>>(query, key_, value,
                                                 Wtq, Wtk, Wtv, bq, bk, bv,
                                                 Qw, Kw, VTw);

    if (SPLIT == 4) {
        float* MLp = Opart + 4ull * 16 * 2048 * 64;
        attn_kernel<4><<<1024, 512, 0, stream>>>(Qw, Kw, VTw, CTXb, Opart, MLp);
        combine_kernel<4><<<2048, 256, 0, stream>>>(Opart, MLp, CTXb);
    } else if (SPLIT == 2) {
        float* MLp = Opart + 2ull * 16 * 2048 * 64;
        attn_kernel<2><<<512, 512, 0, stream>>>(Qw, Kw, VTw, CTXb, Opart, MLp);
        combine_kernel<2><<<2048, 256, 0, stream>>>(Opart, MLp, CTXb);
    } else {
        attn_kernel<1><<<256, 512, 0, stream>>>(Qw, Kw, VTw, CTXb, nullptr, nullptr);
    }

    out_proj_kernel<<<512, 256, 0, stream>>>(CTXb, WoTw, bo, (float*)d_out);
}

// Round 9
// 80.999 us; speedup vs baseline: 2.1569x; 1.7162x over previous
//
#include <hip/hip_runtime.h>

#define B 2
#define S 2048
#define D 512
#define H 8
#define KD 64

typedef __bf16 bf16_t;
typedef __bf16 bf16x8 __attribute__((ext_vector_type(8)));
typedef __bf16 bf16x4 __attribute__((ext_vector_type(4)));
typedef float f32x4 __attribute__((ext_vector_type(4)));

#define QSCALE 0.1803368801111204f   /* 0.125 * log2(e): exp2-domain softmax */

__device__ __forceinline__ void async_copy16(const void* g, void* l) {
    __builtin_amdgcn_global_load_lds(
        (const __attribute__((address_space(1))) void*)g,
        (__attribute__((address_space(3))) void*)l, 16, 0, 0);
}

// ---------------------------------------------------------------------------
// Kernel 0: weight prep (transpose + f32->bf16, once per launch):
//   Wt{q,k,v}[h][col(64)][d(512)]  <-  W*[h][d][col]   (flat: [n=512][k=512])
//   WoT[n(512)][k(512)]            <-  Wo[k][n]
// ---------------------------------------------------------------------------
__global__ __launch_bounds__(256) void prep_kernel(
    const float* __restrict__ Wq, const float* __restrict__ Wk,
    const float* __restrict__ Wv, const float* __restrict__ Wo,
    bf16_t* __restrict__ Wtq, bf16_t* __restrict__ Wtk,
    bf16_t* __restrict__ Wtv, bf16_t* __restrict__ WoT)
{
    __shared__ bf16_t tl[64][72];
    const int blk = blockIdx.x, t = threadIdx.x;

    const float* src; bf16_t* dstbase;
    int ld, r0, c0;
    if (blk < 192) {                       // Wq/Wk/Wv
        const int mat = blk >> 6, h = (blk & 63) >> 3, dt = blk & 7;
        const float* W = (mat == 0) ? Wq : (mat == 1) ? Wk : Wv;
        bf16_t* Wt = (mat == 0) ? Wtq : (mat == 1) ? Wtk : Wtv;
        src = W + (size_t)h * D * KD; dstbase = Wt + (size_t)h * KD * D;
        ld = KD; r0 = dt * 64; c0 = 0;
    } else {                               // Wo
        const int kt = (blk - 192) >> 3, nt = (blk - 192) & 7;
        src = Wo; dstbase = WoT;
        ld = D; r0 = kt * 64; c0 = nt * 64;
    }

    {
        const int r = t >> 2, cq = (t & 3) * 16;
        const float* sp = src + (size_t)(r0 + r) * ld + c0 + cq;
#pragma unroll
        for (int q = 0; q < 4; ++q) {
            const float4 f = *reinterpret_cast<const float4*>(sp + q * 4);
            tl[r][cq + q * 4 + 0] = (bf16_t)f.x; tl[r][cq + q * 4 + 1] = (bf16_t)f.y;
            tl[r][cq + q * 4 + 2] = (bf16_t)f.z; tl[r][cq + q * 4 + 3] = (bf16_t)f.w;
        }
    }
    __syncthreads();
    {
        const int cc = t >> 2, rq = (t & 3) * 16;
        bf16x8 o0, o1;
#pragma unroll
        for (int j = 0; j < 8; ++j) { o0[j] = tl[rq + j][cc]; o1[j] = tl[rq + 8 + j][cc]; }
        bf16_t* dp = dstbase + (size_t)(c0 + cc) * 512 + r0 + rq;
        *reinterpret_cast<bf16x8*>(dp) = o0;
        *reinterpret_cast<bf16x8*>(dp + 8) = o1;
    }
}

// ---------------------------------------------------------------------------
// Kernel 0b: X f32 -> bf16 (so the GEMM A-operand can go via global_load_lds).
// grid (1024, 3) x 256 thr; 8 elems/thread, fully coalesced.
// ---------------------------------------------------------------------------
__global__ __launch_bounds__(256) void xcvt_kernel(
    const float* __restrict__ q, const float* __restrict__ k, const float* __restrict__ v,
    bf16_t* __restrict__ xq, bf16_t* __restrict__ xk, bf16_t* __restrict__ xv)
{
    const int mat = blockIdx.y;
    const float* src = (mat == 0) ? q : (mat == 1) ? k : v;
    bf16_t* dst = (mat == 0) ? xq : (mat == 1) ? xk : xv;
    const size_t i8 = ((size_t)blockIdx.x * 256 + threadIdx.x) * 8;
    const float4 f0 = *reinterpret_cast<const float4*>(src + i8);
    const float4 f1 = *reinterpret_cast<const float4*>(src + i8 + 4);
    bf16x8 o;
    o[0] = (bf16_t)f0.x; o[1] = (bf16_t)f0.y; o[2] = (bf16_t)f0.z; o[3] = (bf16_t)f0.w;
    o[4] = (bf16_t)f1.x; o[5] = (bf16_t)f1.y; o[6] = (bf16_t)f1.z; o[7] = (bf16_t)f1.w;
    *reinterpret_cast<bf16x8*>(dst + i8) = o;
}

// ---------------------------------------------------------------------------
// Shared GEMM mainloop: 64x64 tile, BK=64, double-buffered global_load_lds
// with XOR-swizzled LDS (attn-proven pattern). 4 waves x 32x32 output.
// A [4096][512] bf16 row-major, Bt [512 n][512 k] bf16 row-major.
// acc[mf][nf]: D rows = row0 + wm*32 + mf*16 + 4g+i, cols = n0 + wn*32 + nf*16 + c.
// ---------------------------------------------------------------------------
__device__ __forceinline__ void gemm_tile(
    const bf16_t* __restrict__ A, const bf16_t* __restrict__ Bt,
    int row0, int n0, char* lds, f32x4 (&acc)[2][2])
{
    const int tid = threadIdx.x, wave = tid >> 6, lane = tid & 63;
    const int g = lane >> 4, c = lane & 15;

    // staging: wave stages A rows [wave*16, +16) and B rows [wave*16, +16)
    const int srow8 = lane >> 3, sslot = lane & 7;
    const bf16_t* asrc[2]; const bf16_t* bsrc[2];
#pragma unroll
    for (int j = 0; j < 2; ++j) {
        const int r = wave * 16 + j * 8 + srow8;
        const int ys = (r & 7) ^ (((r >> 3) & 1) << 2);
        asrc[j] = A + (size_t)(row0 + r) * 512 + ((sslot ^ ys) << 3);
        bsrc[j] = Bt + (size_t)(n0 + r) * 512 + ((sslot ^ ys) << 3);
    }
    const int adst = wave * 2048;          // + j*1024
    const int bdst = 8192 + wave * 2048;

    // read-side swizzle: rows differ from c only in bits >=4 -> ys depends on c only
    const int ysr = (c & 7) ^ (((c >> 3) & 1) << 2);
    const int wm = wave >> 1, wn = wave & 1;
    int ard[2], brd[2];
#pragma unroll
    for (int f = 0; f < 2; ++f) {
        ard[f] = (wm * 32 + f * 16 + c) * 128;
        brd[f] = 8192 + (wn * 32 + f * 16 + c) * 128;
    }

#define GSTAGE(bufi, kt)                                                       \
    do { char* bp = lds + (bufi) * 16384;                                      \
        _Pragma("unroll") for (int j = 0; j < 2; ++j) {                        \
            async_copy16(asrc[j] + (kt) * 64, bp + adst + j * 1024);           \
            async_copy16(bsrc[j] + (kt) * 64, bp + bdst + j * 1024);           \
        }                                                                      \
    } while (0)

    int buf = 0;
    GSTAGE(0, 0);
    __syncthreads();
#pragma unroll 1
    for (int kt = 0; kt < 8; ++kt) {
        if (kt < 7) GSTAGE(buf ^ 1, kt + 1);
        const char* bp = lds + buf * 16384;
        __builtin_amdgcn_s_setprio(1);
#pragma unroll
        for (int ksub = 0; ksub < 2; ++ksub) {
            const int so = (((ksub << 2) | g) ^ ysr) << 4;
            bf16x8 bfr[2];
#pragma unroll
            for (int nf = 0; nf < 2; ++nf)
                bfr[nf] = *reinterpret_cast<const bf16x8*>(bp + brd[nf] + so);
#pragma unroll
            for (int mf = 0; mf < 2; ++mf) {
                const bf16x8 afr = *reinterpret_cast<const bf16x8*>(bp + ard[mf] + so);
                acc[mf][0] = __builtin_amdgcn_mfma_f32_16x16x32_bf16(afr, bfr[0], acc[mf][0], 0, 0, 0);
                acc[mf][1] = __builtin_amdgcn_mfma_f32_16x16x32_bf16(afr, bfr[1], acc[mf][1], 0, 0, 0);
            }
        }
        __builtin_amdgcn_s_setprio(0);
        __syncthreads();
        buf ^= 1;
    }
#undef GSTAGE
}

// ---------------------------------------------------------------------------
// Kernel 1: fused QKV projection as tiled GEMM. grid (512, 3) x 256 thr.
// x = ntile*64 + mtile: the 8 blocks sharing an A-panel share one XCD L2.
// ---------------------------------------------------------------------------
__global__ __launch_bounds__(256) void qkv_kernel(
    const bf16_t* __restrict__ xq, const bf16_t* __restrict__ xk, const bf16_t* __restrict__ xv,
    const bf16_t* __restrict__ Wtq, const bf16_t* __restrict__ Wtk, const bf16_t* __restrict__ Wtv,
    const float* __restrict__ bq, const float* __restrict__ bk, const float* __restrict__ bv,
    bf16_t* __restrict__ Qo, bf16_t* __restrict__ Ko, bf16_t* __restrict__ VTo)
{
    __shared__ char lds[2][16384];

    const int mat = blockIdx.y;
    const bf16_t* A    = (mat == 0) ? xq  : (mat == 1) ? xk  : xv;
    const bf16_t* Bt   = (mat == 0) ? Wtq : (mat == 1) ? Wtk : Wtv;
    const float* bias  = (mat == 0) ? bq  : (mat == 1) ? bk  : bv;
    const float scale  = (mat == 0) ? QSCALE : 1.0f;

    const int mtile = blockIdx.x & 63;      // low bits -> XCD
    const int ntile = blockIdx.x >> 6;
    const int row0 = mtile * 64, n0 = ntile * 64;

    const int lane = threadIdx.x & 63;
    const int g = lane >> 4, c = lane & 15;
    const int wave = threadIdx.x >> 6, wm = wave >> 1, wn = wave & 1;

    const f32x4 zero = {0.f, 0.f, 0.f, 0.f};
    f32x4 acc[2][2] = {{zero, zero}, {zero, zero}};
    gemm_tile(A, Bt, row0, n0, &lds[0][0], acc);

#pragma unroll
    for (int mf = 0; mf < 2; ++mf)
#pragma unroll
        for (int nf = 0; nf < 2; ++nf) {
            const int n = n0 + wn * 32 + nf * 16 + c;
            const int h = n >> 6, col = n & 63;
            const float bval = bias[n];
            const int rowb = row0 + wm * 32 + mf * 16 + 4 * g;
            const int b = rowb >> 11, s0 = rowb & 2047;
            const int bh = b * H + h;
            if (mat < 2) {
                bf16_t* outp = (mat == 0) ? Qo : Ko;
#pragma unroll
                for (int i = 0; i < 4; ++i)
                    outp[((size_t)bh * S + s0 + i) * KD + col] =
                        (bf16_t)((acc[mf][nf][i] + bval) * scale);
            } else {
                bf16x4 o;
#pragma unroll
                for (int i = 0; i < 4; ++i) o[i] = (bf16_t)(acc[mf][nf][i] + bval);
                *reinterpret_cast<bf16x4*>(VTo + ((size_t)bh * KD + col) * S + s0) = o;
            }
        }
}

// ---------------------------------------------------------------------------
// Kernel 2: flash attention, KV-split over grid (flash-decode). Unchanged.
// ---------------------------------------------------------------------------
template <int SPLIT>
__global__ __launch_bounds__(512) void attn_kernel(
    const bf16_t* __restrict__ Q, const bf16_t* __restrict__ Km,
    const bf16_t* __restrict__ VT,
    bf16_t* __restrict__ CTX, float* __restrict__ Opart, float* __restrict__ ML)
{
    __shared__ char kv_lds[2][16384];

    const int hw = blockIdx.x;
    const int xcd = hw & 7;
    const int idx = hw >> 3;
    const int bh = xcd * 2 + (idx >= 16 * SPLIT ? 1 : 0);
    const int r2 = idx & (16 * SPLIT - 1);
    const int chunk = r2 >> 4;
    const int stile = r2 & 15;
    const int b = bh >> 3, h = bh & (H - 1);

    const int tid = threadIdx.x, wave = tid >> 6, lane = tid & 63;
    const int g = lane >> 4, c = lane & 15;
    const int q0 = stile * 128 + wave * 16;
    const int kvbeg = chunk * (S / SPLIT);
    const int NT = (S / SPLIT) / 64;

    const bf16_t* kg = Km + (size_t)bh * S * KD;
    const bf16_t* vg = VT + (size_t)bh * KD * S;

    const bf16_t* qp = Q + ((size_t)bh * S + q0 + c) * KD;
    const bf16x8 qlo = *reinterpret_cast<const bf16x8*>(qp + g * 8);
    const bf16x8 qhi = *reinterpret_cast<const bf16x8*>(qp + 32 + g * 8);

    int koff[4][2], voff[4][2];
#pragma unroll
    for (int tt = 0; tt < 4; ++tt) {
        const int row = 8 * (c >> 2) + (c & 3) + 4 * (tt & 1) + 32 * (tt >> 1);
        const int ys = (row & 7) ^ (((row >> 3) & 1) << 2);
        koff[tt][0] = row * 128 + ((g * 16) ^ (ys << 4));
        koff[tt][1] = row * 128 + ((64 + g * 16) ^ (ys << 4));
    }
#pragma unroll
    for (int ct = 0; ct < 4; ++ct) {
        const int row = ct * 16 + c;
        const int ys = (row & 7) ^ (((row >> 3) & 1) << 2);
        voff[ct][0] = 8192 + row * 128 + ((g * 16) ^ (ys << 4));
        voff[ct][1] = 8192 + row * 128 + ((64 + g * 16) ^ (ys << 4));
    }

    const int srow = lane >> 3, sslot = lane & 7;
    const int kwv = wave & 3;
    const int krow0a = kwv * 16, krow0b = kwv * 16 + 8;
    const int rowa = krow0a + srow, rowb = krow0b + srow;
    const int ysa = (rowa & 7) ^ (((rowa >> 3) & 1) << 2);
    const int ysb = (rowb & 7) ^ (((rowb >> 3) & 1) << 2);
    const int ssa = sslot ^ ysa, ssb = sslot ^ ysb;

    const f32x4 zero = {0.f, 0.f, 0.f, 0.f};
    f32x4 acc[4] = {zero, zero, zero, zero};
    float m_run = -1e30f, l_run = 0.f;

#define STAGE(bufidx, kv0)                                                        \
    do {                                                                          \
        char* bp = kv_lds[0] + (bufidx) * 16384;                                  \
        if (wave < 4) {                                                           \
            async_copy16(kg + (size_t)((kv0) + rowa) * KD + ssa * 8, bp + krow0a * 128); \
            async_copy16(kg + (size_t)((kv0) + rowb) * KD + ssb * 8, bp + krow0b * 128); \
        } else {                                                                  \
            async_copy16(vg + (size_t)rowa * S + (kv0) + ssa * 8, bp + 8192 + krow0a * 128); \
            async_copy16(vg + (size_t)rowb * S + (kv0) + ssb * 8, bp + 8192 + krow0b * 128); \
        }                                                                         \
    } while (0)

    STAGE(0, kvbeg);
    __syncthreads();

    int buf = 0;
    for (int t = 0; t < NT; ++t) {
        if (t < NT - 1) STAGE(buf ^ 1, kvbeg + (t + 1) * 64);
        const char* kb = kv_lds[0] + buf * 16384;

        f32x4 sc[4];
        __builtin_amdgcn_s_setprio(1);
#pragma unroll
        for (int tt = 0; tt < 4; ++tt) {
            const bf16x8 k0f = *reinterpret_cast<const bf16x8*>(kb + koff[tt][0]);
            const bf16x8 k1f = *reinterpret_cast<const bf16x8*>(kb + koff[tt][1]);
            f32x4 z = zero;
            z = __builtin_amdgcn_mfma_f32_16x16x32_bf16(k0f, qlo, z, 0, 0, 0);
            sc[tt] = __builtin_amdgcn_mfma_f32_16x16x32_bf16(k1f, qhi, z, 0, 0, 0);
        }
        __builtin_amdgcn_s_setprio(0);

        const float a0 = fmaxf(fmaxf(sc[0][0], sc[0][1]), fmaxf(sc[0][2], sc[0][3]));
        const float a1 = fmaxf(fmaxf(sc[1][0], sc[1][1]), fmaxf(sc[1][2], sc[1][3]));
        const float a2 = fmaxf(fmaxf(sc[2][0], sc[2][1]), fmaxf(sc[2][2], sc[2][3]));
        const float a3 = fmaxf(fmaxf(sc[3][0], sc[3][1]), fmaxf(sc[3][2], sc[3][3]));
        float pm = fmaxf(fmaxf(a0, a1), fmaxf(a2, a3));
        if (!__all(pm <= m_run + 8.0f)) {
            pm = fmaxf(pm, __shfl_xor(pm, 16));
            pm = fmaxf(pm, __shfl_xor(pm, 32));
            const float mn = fmaxf(m_run, pm);
            const float fs = exp2f(m_run - mn);
            m_run = mn;
            l_run *= fs;
#pragma unroll
            for (int ct = 0; ct < 4; ++ct) acc[ct] = acc[ct] * fs;
        }

        bf16x8 f0, f1;
        float ls = 0.f;
#pragma unroll
        for (int i = 0; i < 4; ++i) {
            const float p0 = exp2f(sc[0][i] - m_run);
            const float p1 = exp2f(sc[1][i] - m_run);
            const float p2 = exp2f(sc[2][i] - m_run);
            const float p3 = exp2f(sc[3][i] - m_run);
            f0[i] = (bf16_t)p0; f0[4 + i] = (bf16_t)p1;
            f1[i] = (bf16_t)p2; f1[4 + i] = (bf16_t)p3;
            ls += (p0 + p1) + (p2 + p3);
        }
        l_run += ls;

        __builtin_amdgcn_s_setprio(1);
#pragma unroll
        for (int ct = 0; ct < 4; ++ct) {
            const bf16x8 v0f = *reinterpret_cast<const bf16x8*>(kb + voff[ct][0]);
            const bf16x8 v1f = *reinterpret_cast<const bf16x8*>(kb + voff[ct][1]);
            acc[ct] = __builtin_amdgcn_mfma_f32_16x16x32_bf16(v0f, f0, acc[ct], 0, 0, 0);
            acc[ct] = __builtin_amdgcn_mfma_f32_16x16x32_bf16(v1f, f1, acc[ct], 0, 0, 0);
        }
        __builtin_amdgcn_s_setprio(0);

        __syncthreads();
        buf ^= 1;
    }
#undef STAGE

    l_run += __shfl_xor(l_run, 16);
    l_run += __shfl_xor(l_run, 32);

    if constexpr (SPLIT == 1) {
        const float inv = 1.0f / l_run;
        bf16_t* crow = CTX + ((size_t)b * S + q0 + c) * 512 + h * 64;
#pragma unroll
        for (int ct = 0; ct < 4; ++ct) {
            bf16x4 o;
#pragma unroll
            for (int i = 0; i < 4; ++i) o[i] = (bf16_t)(acc[ct][i] * inv);
            *reinterpret_cast<bf16x4*>(crow + ct * 16 + 4 * g) = o;
        }
    } else {
        const size_t prow = (size_t)(chunk * 16 + bh) * 2048 + q0 + c;
        float* orow = Opart + prow * 64;
#pragma unroll
        for (int ct = 0; ct < 4; ++ct) {
            f32x4 o = acc[ct];
            *reinterpret_cast<f32x4*>(orow + ct * 16 + 4 * g) = o;
        }
        if (g == 0) {
            float2 ml; ml.x = m_run; ml.y = l_run;
            *reinterpret_cast<float2*>(ML + prow * 2) = ml;
        }
    }
}

// ---------------------------------------------------------------------------
// Kernel 2b: combine KV-split partials -> bf16 ctx. Unchanged.
// ---------------------------------------------------------------------------
template <int SPLIT>
__global__ __launch_bounds__(256) void combine_kernel(
    const float* __restrict__ Opart, const float* __restrict__ ML,
    bf16_t* __restrict__ CTX)
{
    const int gid = blockIdx.x * 256 + threadIdx.x;
    const int d4 = gid & 15, rowh = gid >> 4;
    const int bh = rowh >> 11, s = rowh & 2047;
    const int b = bh >> 3, h = bh & (H - 1);

    float m[SPLIT], l[SPLIT], M = -1e30f;
#pragma unroll
    for (int i = 0; i < SPLIT; ++i) {
        const float2 v = *reinterpret_cast<const float2*>(
            ML + ((size_t)(i * 16 + bh) * 2048 + s) * 2);
        m[i] = v.x; l[i] = v.y;
        M = fmaxf(M, m[i]);
    }
    f32x4 o = {0.f, 0.f, 0.f, 0.f};
    float wsum = 0.f;
#pragma unroll
    for (int i = 0; i < SPLIT; ++i) {
        const float w = exp2f(m[i] - M);
        wsum += w * l[i];
        const f32x4 ov = *reinterpret_cast<const f32x4*>(
            Opart + ((size_t)(i * 16 + bh) * 2048 + s) * 64 + d4 * 4);
        o += ov * w;
    }
    const float inv = 1.0f / wsum;
    bf16x4 r;
#pragma unroll
    for (int i = 0; i < 4; ++i) r[i] = (bf16_t)(o[i] * inv);
    *reinterpret_cast<bf16x4*>(CTX + ((size_t)b * S + s) * 512 + h * 64 + d4 * 4) = r;
}

// ---------------------------------------------------------------------------
// Kernel 3: output projection via the same GEMM tile. grid 512 x 256 thr.
// ---------------------------------------------------------------------------
__global__ __launch_bounds__(256) void out_proj_kernel(
    const bf16_t* __restrict__ CTX,
    const bf16_t* __restrict__ WoT,
    const float* __restrict__ bo,
    float* __restrict__ out)
{
    __shared__ char lds[2][16384];

    const int mtile = blockIdx.x & 63;      // low bits -> XCD
    const int ntile = blockIdx.x >> 6;
    const int row0 = mtile * 64, n0 = ntile * 64;

    const int lane = threadIdx.x & 63;
    const int g = lane >> 4, c = lane & 15;
    const int wave = threadIdx.x >> 6, wm = wave >> 1, wn = wave & 1;

    const f32x4 zero = {0.f, 0.f, 0.f, 0.f};
    f32x4 acc[2][2] = {{zero, zero}, {zero, zero}};
    gemm_tile(CTX, WoT, row0, n0, &lds[0][0], acc);

#pragma unroll
    for (int mf = 0; mf < 2; ++mf)
#pragma unroll
        for (int nf = 0; nf < 2; ++nf) {
            const int n = n0 + wn * 32 + nf * 16 + c;
            const float bval = bo[n];
            const int rowb = row0 + wm * 32 + mf * 16 + 4 * g;
#pragma unroll
            for (int i = 0; i < 4; ++i)
                out[(size_t)(rowb + i) * 512 + n] = acc[mf][nf][i] + bval;
        }
}

// ---------------------------------------------------------------------------
extern "C" void kernel_launch(void* const* d_in, const int* in_sizes, int n_in,
                              void* d_out, int out_size, void* d_ws, size_t ws_size,
                              hipStream_t stream) {
    const float* query = (const float*)d_in[0];
    const float* key_  = (const float*)d_in[1];
    const float* value = (const float*)d_in[2];
    const float* Wq = (const float*)d_in[3];
    const float* bq = (const float*)d_in[4];
    const float* Wk = (const float*)d_in[5];
    const float* bk = (const float*)d_in[6];
    const float* Wv = (const float*)d_in[7];
    const float* bv = (const float*)d_in[8];
    const float* Wo = (const float*)d_in[9];
    const float* bo = (const float*)d_in[10];

    char* wsb = (char*)d_ws;
    bf16_t* Qw   = (bf16_t*)(wsb);                       // 4 MB
    bf16_t* Kw   = (bf16_t*)(wsb + (4u  << 20));         // 4 MB
    bf16_t* VTw  = (bf16_t*)(wsb + (8u  << 20));         // 4 MB
    bf16_t* CTXb = (bf16_t*)(wsb + (12u << 20));         // 4 MB
    bf16_t* Wtq  = (bf16_t*)(wsb + (16u << 20));         // 512 KB
    bf16_t* Wtk  = Wtq + 8 * 64 * 512;
    bf16_t* Wtv  = Wtk + 8 * 64 * 512;
    bf16_t* WoTw = (bf16_t*)(wsb + (18u << 20));         // 512 KB
    bf16_t* Xq   = (bf16_t*)(wsb + (20u << 20));         // 4 MB
    bf16_t* Xk   = (bf16_t*)(wsb + (24u << 20));         // 4 MB
    bf16_t* Xv   = (bf16_t*)(wsb + (28u << 20));         // 4 MB
    float*  Opart = (float*)(wsb + (32u << 20));         // SPLIT x 8 MB

    const int SPLIT = (ws_size >= (70ull << 20)) ? 4
                    : (ws_size >= (52ull << 20)) ? 2 : 1;

    prep_kernel<<<256, 256, 0, stream>>>(Wq, Wk, Wv, Wo, Wtq, Wtk, Wtv, WoTw);
    xcvt_kernel<<<dim3(1024, 3), 256, 0, stream>>>(query, key_, value, Xq, Xk, Xv);
    qkv_kernel<<<dim3(512, 3), 256, 0, stream>>>(Xq, Xk, Xv,
                                                 Wtq, Wtk, Wtv, bq, bk, bv,
                                                 Qw, Kw, VTw);

    if (SPLIT == 4) {
        float* MLp = Opart + 4ull * 16 * 2048 * 64;
        attn_kernel<4><<<1024, 512, 0, stream>>>(Qw, Kw, VTw, CTXb, Opart, MLp);
        combine_kernel<4><<<2048, 256, 0, stream>>>(Opart, MLp, CTXb);
    } else if (SPLIT == 2) {
        float* MLp = Opart + 2ull * 16 * 2048 * 64;
        attn_kernel<2><<<512, 512, 0, stream>>>(Qw, Kw, VTw, CTXb, Opart, MLp);
        combine_kernel<2><<<2048, 256, 0, stream>>>(Opart, MLp, CTXb);
    } else {
        attn_kernel<1><<<256, 512, 0, stream>>>(Qw, Kw, VTw, CTXb, nullptr, nullptr);
    }

    out_proj_kernel<<<512, 256, 0, stream>>>(CTXb, WoTw, bo, (float*)d_out);
}

// Round 10
// 76.116 us; speedup vs baseline: 2.2952x; 1.0642x over previous
//
#include <hip/hip_runtime.h>

#define B 2
#define S 2048
#define D 512
#define H 8
#define KD 64

typedef __bf16 bf16_t;
typedef __bf16 bf16x8 __attribute__((ext_vector_type(8)));
typedef __bf16 bf16x4 __attribute__((ext_vector_type(4)));
typedef float f32x4 __attribute__((ext_vector_type(4)));

#define QSCALE 0.1803368801111204f   /* 0.125 * log2(e): exp2-domain softmax */

__device__ __forceinline__ void async_copy16(const void* g, void* l) {
    __builtin_amdgcn_global_load_lds(
        (const __attribute__((address_space(1))) void*)g,
        (__attribute__((address_space(3))) void*)l, 16, 0, 0);
}

__device__ __forceinline__ float max3f(float a, float b, float c) {
    float d;
    asm("v_max3_f32 %0, %1, %2, %3" : "=v"(d) : "v"(a), "v"(b), "v"(c));
    return d;
}

// ---------------------------------------------------------------------------
// Kernel 0: weight prep (transpose + f32->bf16, once per launch):
//   Wt{q,k,v}[h][col(64)][d(512)]  <-  W*[h][d][col]   (flat: [n=512][k=512])
//   WoT[n(512)][k(512)]            <-  Wo[k][n]
// ---------------------------------------------------------------------------
__global__ __launch_bounds__(256) void prep_kernel(
    const float* __restrict__ Wq, const float* __restrict__ Wk,
    const float* __restrict__ Wv, const float* __restrict__ Wo,
    bf16_t* __restrict__ Wtq, bf16_t* __restrict__ Wtk,
    bf16_t* __restrict__ Wtv, bf16_t* __restrict__ WoT)
{
    __shared__ bf16_t tl[64][72];
    const int blk = blockIdx.x, t = threadIdx.x;

    const float* src; bf16_t* dstbase;
    int ld, r0, c0;
    if (blk < 192) {                       // Wq/Wk/Wv
        const int mat = blk >> 6, h = (blk & 63) >> 3, dt = blk & 7;
        const float* W = (mat == 0) ? Wq : (mat == 1) ? Wk : Wv;
        bf16_t* Wt = (mat == 0) ? Wtq : (mat == 1) ? Wtk : Wtv;
        src = W + (size_t)h * D * KD; dstbase = Wt + (size_t)h * KD * D;
        ld = KD; r0 = dt * 64; c0 = 0;
    } else {                               // Wo
        const int kt = (blk - 192) >> 3, nt = (blk - 192) & 7;
        src = Wo; dstbase = WoT;
        ld = D; r0 = kt * 64; c0 = nt * 64;
    }

    {
        const int r = t >> 2, cq = (t & 3) * 16;
        const float* sp = src + (size_t)(r0 + r) * ld + c0 + cq;
#pragma unroll
        for (int q = 0; q < 4; ++q) {
            const float4 f = *reinterpret_cast<const float4*>(sp + q * 4);
            tl[r][cq + q * 4 + 0] = (bf16_t)f.x; tl[r][cq + q * 4 + 1] = (bf16_t)f.y;
            tl[r][cq + q * 4 + 2] = (bf16_t)f.z; tl[r][cq + q * 4 + 3] = (bf16_t)f.w;
        }
    }
    __syncthreads();
    {
        const int cc = t >> 2, rq = (t & 3) * 16;
        bf16x8 o0, o1;
#pragma unroll
        for (int j = 0; j < 8; ++j) { o0[j] = tl[rq + j][cc]; o1[j] = tl[rq + 8 + j][cc]; }
        bf16_t* dp = dstbase + (size_t)(c0 + cc) * 512 + r0 + rq;
        *reinterpret_cast<bf16x8*>(dp) = o0;
        *reinterpret_cast<bf16x8*>(dp + 8) = o1;
    }
}

// ---------------------------------------------------------------------------
// Kernel 0b: X f32 -> bf16. grid (1024, 3) x 256 thr.
// ---------------------------------------------------------------------------
__global__ __launch_bounds__(256) void xcvt_kernel(
    const float* __restrict__ q, const float* __restrict__ k, const float* __restrict__ v,
    bf16_t* __restrict__ xq, bf16_t* __restrict__ xk, bf16_t* __restrict__ xv)
{
    const int mat = blockIdx.y;
    const float* src = (mat == 0) ? q : (mat == 1) ? k : v;
    bf16_t* dst = (mat == 0) ? xq : (mat == 1) ? xk : xv;
    const size_t i8 = ((size_t)blockIdx.x * 256 + threadIdx.x) * 8;
    const float4 f0 = *reinterpret_cast<const float4*>(src + i8);
    const float4 f1 = *reinterpret_cast<const float4*>(src + i8 + 4);
    bf16x8 o;
    o[0] = (bf16_t)f0.x; o[1] = (bf16_t)f0.y; o[2] = (bf16_t)f0.z; o[3] = (bf16_t)f0.w;
    o[4] = (bf16_t)f1.x; o[5] = (bf16_t)f1.y; o[6] = (bf16_t)f1.z; o[7] = (bf16_t)f1.w;
    *reinterpret_cast<bf16x8*>(dst + i8) = o;
}

// ---------------------------------------------------------------------------
// Shared GEMM mainloop: 64x64 tile, BK=64, double-buffered global_load_lds
// with XOR-swizzled LDS. 4 waves x 32x32 output. (Verified in R9.)
// ---------------------------------------------------------------------------
__device__ __forceinline__ void gemm_tile(
    const bf16_t* __restrict__ A, const bf16_t* __restrict__ Bt,
    int row0, int n0, char* lds, f32x4 (&acc)[2][2])
{
    const int tid = threadIdx.x, wave = tid >> 6, lane = tid & 63;
    const int g = lane >> 4, c = lane & 15;

    const int srow8 = lane >> 3, sslot = lane & 7;
    const bf16_t* asrc[2]; const bf16_t* bsrc[2];
#pragma unroll
    for (int j = 0; j < 2; ++j) {
        const int r = wave * 16 + j * 8 + srow8;
        const int ys = (r & 7) ^ (((r >> 3) & 1) << 2);
        asrc[j] = A + (size_t)(row0 + r) * 512 + ((sslot ^ ys) << 3);
        bsrc[j] = Bt + (size_t)(n0 + r) * 512 + ((sslot ^ ys) << 3);
    }
    const int adst = wave * 2048;
    const int bdst = 8192 + wave * 2048;

    const int ysr = (c & 7) ^ (((c >> 3) & 1) << 2);
    const int wm = wave >> 1, wn = wave & 1;
    int ard[2], brd[2];
#pragma unroll
    for (int f = 0; f < 2; ++f) {
        ard[f] = (wm * 32 + f * 16 + c) * 128;
        brd[f] = 8192 + (wn * 32 + f * 16 + c) * 128;
    }

#define GSTAGE(bufi, kt)                                                       \
    do { char* bp = lds + (bufi) * 16384;                                      \
        _Pragma("unroll") for (int j = 0; j < 2; ++j) {                        \
            async_copy16(asrc[j] + (kt) * 64, bp + adst + j * 1024);           \
            async_copy16(bsrc[j] + (kt) * 64, bp + bdst + j * 1024);           \
        }                                                                      \
    } while (0)

    int buf = 0;
    GSTAGE(0, 0);
    __syncthreads();
#pragma unroll 1
    for (int kt = 0; kt < 8; ++kt) {
        if (kt < 7) GSTAGE(buf ^ 1, kt + 1);
        const char* bp = lds + buf * 16384;
        __builtin_amdgcn_s_setprio(1);
#pragma unroll
        for (int ksub = 0; ksub < 2; ++ksub) {
            const int so = (((ksub << 2) | g) ^ ysr) << 4;
            bf16x8 bfr[2];
#pragma unroll
            for (int nf = 0; nf < 2; ++nf)
                bfr[nf] = *reinterpret_cast<const bf16x8*>(bp + brd[nf] + so);
#pragma unroll
            for (int mf = 0; mf < 2; ++mf) {
                const bf16x8 afr = *reinterpret_cast<const bf16x8*>(bp + ard[mf] + so);
                acc[mf][0] = __builtin_amdgcn_mfma_f32_16x16x32_bf16(afr, bfr[0], acc[mf][0], 0, 0, 0);
                acc[mf][1] = __builtin_amdgcn_mfma_f32_16x16x32_bf16(afr, bfr[1], acc[mf][1], 0, 0, 0);
            }
        }
        __builtin_amdgcn_s_setprio(0);
        __syncthreads();
        buf ^= 1;
    }
#undef GSTAGE
}

// ---------------------------------------------------------------------------
// Kernel 1: fused QKV projection as tiled GEMM. grid (512, 3) x 256 thr.
// ---------------------------------------------------------------------------
__global__ __launch_bounds__(256) void qkv_kernel(
    const bf16_t* __restrict__ xq, const bf16_t* __restrict__ xk, const bf16_t* __restrict__ xv,
    const bf16_t* __restrict__ Wtq, const bf16_t* __restrict__ Wtk, const bf16_t* __restrict__ Wtv,
    const float* __restrict__ bq, const float* __restrict__ bk, const float* __restrict__ bv,
    bf16_t* __restrict__ Qo, bf16_t* __restrict__ Ko, bf16_t* __restrict__ VTo)
{
    __shared__ char lds[2][16384];

    const int mat = blockIdx.y;
    const bf16_t* A    = (mat == 0) ? xq  : (mat == 1) ? xk  : xv;
    const bf16_t* Bt   = (mat == 0) ? Wtq : (mat == 1) ? Wtk : Wtv;
    const float* bias  = (mat == 0) ? bq  : (mat == 1) ? bk  : bv;
    const float scale  = (mat == 0) ? QSCALE : 1.0f;

    const int mtile = blockIdx.x & 63;      // low bits -> XCD
    const int ntile = blockIdx.x >> 6;
    const int row0 = mtile * 64, n0 = ntile * 64;

    const int lane = threadIdx.x & 63;
    const int g = lane >> 4, c = lane & 15;
    const int wave = threadIdx.x >> 6, wm = wave >> 1, wn = wave & 1;

    const f32x4 zero = {0.f, 0.f, 0.f, 0.f};
    f32x4 acc[2][2] = {{zero, zero}, {zero, zero}};
    gemm_tile(A, Bt, row0, n0, &lds[0][0], acc);

#pragma unroll
    for (int mf = 0; mf < 2; ++mf)
#pragma unroll
        for (int nf = 0; nf < 2; ++nf) {
            const int n = n0 + wn * 32 + nf * 16 + c;
            const int h = n >> 6, col = n & 63;
            const float bval = bias[n];
            const int rowb = row0 + wm * 32 + mf * 16 + 4 * g;
            const int b = rowb >> 11, s0 = rowb & 2047;
            const int bh = b * H + h;
            if (mat < 2) {
                bf16_t* outp = (mat == 0) ? Qo : Ko;
#pragma unroll
                for (int i = 0; i < 4; ++i)
                    outp[((size_t)bh * S + s0 + i) * KD + col] =
                        (bf16_t)((acc[mf][nf][i] + bval) * scale);
            } else {
                bf16x4 o;
#pragma unroll
                for (int i = 0; i < 4; ++i) o[i] = (bf16_t)(acc[mf][nf][i] + bval);
                *reinterpret_cast<bf16x4*>(VTo + ((size_t)bh * KD + col) * S + s0) = o;
            }
        }
}

// ---------------------------------------------------------------------------
// Kernel 2: flash attention, KV-split. VALU-trimmed softmax:
//  - row max via v_max3 (8 ops);
//  - l computed on the MATRIX pipe: acc_l = mfma(ones, P, acc_l) — no sum
//    tree, no post-loop shuffles; rescale scales acc_l like any other acc.
// ---------------------------------------------------------------------------
template <int SPLIT>
__global__ __launch_bounds__(512) void attn_kernel(
    const bf16_t* __restrict__ Q, const bf16_t* __restrict__ Km,
    const bf16_t* __restrict__ VT,
    bf16_t* __restrict__ CTX, bf16_t* __restrict__ Opart, float* __restrict__ ML)
{
    __shared__ char kv_lds[2][16384];

    const int hw = blockIdx.x;
    const int xcd = hw & 7;
    const int idx = hw >> 3;
    const int bh = xcd * 2 + (idx >= 16 * SPLIT ? 1 : 0);
    const int r2 = idx & (16 * SPLIT - 1);
    const int chunk = r2 >> 4;
    const int stile = r2 & 15;
    const int b = bh >> 3, h = bh & (H - 1);

    const int tid = threadIdx.x, wave = tid >> 6, lane = tid & 63;
    const int g = lane >> 4, c = lane & 15;
    const int q0 = stile * 128 + wave * 16;
    const int kvbeg = chunk * (S / SPLIT);
    const int NT = (S / SPLIT) / 64;

    const bf16_t* kg = Km + (size_t)bh * S * KD;
    const bf16_t* vg = VT + (size_t)bh * KD * S;

    const bf16_t* qp = Q + ((size_t)bh * S + q0 + c) * KD;
    const bf16x8 qlo = *reinterpret_cast<const bf16x8*>(qp + g * 8);
    const bf16x8 qhi = *reinterpret_cast<const bf16x8*>(qp + 32 + g * 8);

    bf16x8 ones;
#pragma unroll
    for (int i = 0; i < 8; ++i) ones[i] = (bf16_t)1.0f;

    int koff[4][2], voff[4][2];
#pragma unroll
    for (int tt = 0; tt < 4; ++tt) {
        const int row = 8 * (c >> 2) + (c & 3) + 4 * (tt & 1) + 32 * (tt >> 1);
        const int ys = (row & 7) ^ (((row >> 3) & 1) << 2);
        koff[tt][0] = row * 128 + ((g * 16) ^ (ys << 4));
        koff[tt][1] = row * 128 + ((64 + g * 16) ^ (ys << 4));
    }
#pragma unroll
    for (int ct = 0; ct < 4; ++ct) {
        const int row = ct * 16 + c;
        const int ys = (row & 7) ^ (((row >> 3) & 1) << 2);
        voff[ct][0] = 8192 + row * 128 + ((g * 16) ^ (ys << 4));
        voff[ct][1] = 8192 + row * 128 + ((64 + g * 16) ^ (ys << 4));
    }

    const int srow = lane >> 3, sslot = lane & 7;
    const int kwv = wave & 3;
    const int krow0a = kwv * 16, krow0b = kwv * 16 + 8;
    const int rowa = krow0a + srow, rowb = krow0b + srow;
    const int ysa = (rowa & 7) ^ (((rowa >> 3) & 1) << 2);
    const int ysb = (rowb & 7) ^ (((rowb >> 3) & 1) << 2);
    const int ssa = sslot ^ ysa, ssb = sslot ^ ysb;

    const f32x4 zero = {0.f, 0.f, 0.f, 0.f};
    f32x4 acc[4] = {zero, zero, zero, zero};
    f32x4 accl = zero;                 // accl[i] = l for q = q0+c (all i equal)
    float m_run = -1e30f;

#define STAGE(bufidx, kv0)                                                        \
    do {                                                                          \
        char* bp = kv_lds[0] + (bufidx) * 16384;                                  \
        if (wave < 4) {                                                           \
            async_copy16(kg + (size_t)((kv0) + rowa) * KD + ssa * 8, bp + krow0a * 128); \
            async_copy16(kg + (size_t)((kv0) + rowb) * KD + ssb * 8, bp + krow0b * 128); \
        } else {                                                                  \
            async_copy16(vg + (size_t)rowa * S + (kv0) + ssa * 8, bp + 8192 + krow0a * 128); \
            async_copy16(vg + (size_t)rowb * S + (kv0) + ssb * 8, bp + 8192 + krow0b * 128); \
        }                                                                         \
    } while (0)

    STAGE(0, kvbeg);
    __syncthreads();

    int buf = 0;
    for (int t = 0; t < NT; ++t) {
        if (t < NT - 1) STAGE(buf ^ 1, kvbeg + (t + 1) * 64);
        const char* kb = kv_lds[0] + buf * 16384;

        // ---- QK^T (swapped)
        f32x4 sc[4];
        __builtin_amdgcn_s_setprio(1);
#pragma unroll
        for (int tt = 0; tt < 4; ++tt) {
            const bf16x8 k0f = *reinterpret_cast<const bf16x8*>(kb + koff[tt][0]);
            const bf16x8 k1f = *reinterpret_cast<const bf16x8*>(kb + koff[tt][1]);
            f32x4 z = zero;
            z = __builtin_amdgcn_mfma_f32_16x16x32_bf16(k0f, qlo, z, 0, 0, 0);
            sc[tt] = __builtin_amdgcn_mfma_f32_16x16x32_bf16(k1f, qhi, z, 0, 0, 0);
        }
        __builtin_amdgcn_s_setprio(0);

        // ---- row max via v_max3: 5 + 2 + 1 ops
        const float m0 = max3f(sc[0][0], sc[0][1], sc[0][2]);
        const float m1 = max3f(sc[0][3], sc[1][0], sc[1][1]);
        const float m2 = max3f(sc[1][2], sc[1][3], sc[2][0]);
        const float m3 = max3f(sc[2][1], sc[2][2], sc[2][3]);
        const float m4 = max3f(sc[3][0], sc[3][1], sc[3][2]);
        float pm = fmaxf(max3f(max3f(m0, m1, m2), m3, m4), sc[3][3]);
        if (!__all(pm <= m_run + 8.0f)) {
            pm = fmaxf(pm, __shfl_xor(pm, 16));
            pm = fmaxf(pm, __shfl_xor(pm, 32));
            const float mn = fmaxf(m_run, pm);
            const float fs = exp2f(m_run - mn);
            m_run = mn;
            accl = accl * fs;
#pragma unroll
            for (int ct = 0; ct < 4; ++ct) acc[ct] = acc[ct] * fs;
        }

        bf16x8 f0, f1;
#pragma unroll
        for (int i = 0; i < 4; ++i) {
            f0[i]     = (bf16_t)exp2f(sc[0][i] - m_run);
            f0[4 + i] = (bf16_t)exp2f(sc[1][i] - m_run);
            f1[i]     = (bf16_t)exp2f(sc[2][i] - m_run);
            f1[4 + i] = (bf16_t)exp2f(sc[3][i] - m_run);
        }

        // ---- PV + l on the matrix pipe
        __builtin_amdgcn_s_setprio(1);
        accl = __builtin_amdgcn_mfma_f32_16x16x32_bf16(ones, f0, accl, 0, 0, 0);
        accl = __builtin_amdgcn_mfma_f32_16x16x32_bf16(ones, f1, accl, 0, 0, 0);
#pragma unroll
        for (int ct = 0; ct < 4; ++ct) {
            const bf16x8 v0f = *reinterpret_cast<const bf16x8*>(kb + voff[ct][0]);
            const bf16x8 v1f = *reinterpret_cast<const bf16x8*>(kb + voff[ct][1]);
            acc[ct] = __builtin_amdgcn_mfma_f32_16x16x32_bf16(v0f, f0, acc[ct], 0, 0, 0);
            acc[ct] = __builtin_amdgcn_mfma_f32_16x16x32_bf16(v1f, f1, acc[ct], 0, 0, 0);
        }
        __builtin_amdgcn_s_setprio(0);

        __syncthreads();
        buf ^= 1;
    }
#undef STAGE

    const float l_tot = accl[0];

    if constexpr (SPLIT == 1) {
        const float inv = 1.0f / l_tot;
        bf16_t* crow = CTX + ((size_t)b * S + q0 + c) * 512 + h * 64;
#pragma unroll
        for (int ct = 0; ct < 4; ++ct) {
            bf16x4 o;
#pragma unroll
            for (int i = 0; i < 4; ++i) o[i] = (bf16_t)(acc[ct][i] * inv);
            *reinterpret_cast<bf16x4*>(crow + ct * 16 + 4 * g) = o;
        }
    } else {
        const size_t prow = (size_t)(chunk * 16 + bh) * 2048 + q0 + c;
        bf16_t* orow = Opart + prow * 64;
#pragma unroll
        for (int ct = 0; ct < 4; ++ct) {
            bf16x4 o;
#pragma unroll
            for (int i = 0; i < 4; ++i) o[i] = (bf16_t)acc[ct][i];
            *reinterpret_cast<bf16x4*>(orow + ct * 16 + 4 * g) = o;
        }
        if (g == 0) {
            float2 ml; ml.x = m_run; ml.y = l_tot;
            *reinterpret_cast<float2*>(ML + prow * 2) = ml;
        }
    }
}

// ---------------------------------------------------------------------------
// Kernel 2b: combine KV-split partials (bf16 O, f32 m/l) -> bf16 ctx.
// ---------------------------------------------------------------------------
template <int SPLIT>
__global__ __launch_bounds__(256) void combine_kernel(
    const bf16_t* __restrict__ Opart, const float* __restrict__ ML,
    bf16_t* __restrict__ CTX)
{
    const int gid = blockIdx.x * 256 + threadIdx.x;
    const int d4 = gid & 15, rowh = gid >> 4;
    const int bh = rowh >> 11, s = rowh & 2047;
    const int b = bh >> 3, h = bh & (H - 1);

    float m[SPLIT], l[SPLIT], M = -1e30f;
#pragma unroll
    for (int i = 0; i < SPLIT; ++i) {
        const float2 v = *reinterpret_cast<const float2*>(
            ML + ((size_t)(i * 16 + bh) * 2048 + s) * 2);
        m[i] = v.x; l[i] = v.y;
        M = fmaxf(M, m[i]);
    }
    f32x4 o = {0.f, 0.f, 0.f, 0.f};
    float wsum = 0.f;
#pragma unroll
    for (int i = 0; i < SPLIT; ++i) {
        const float w = exp2f(m[i] - M);
        wsum += w * l[i];
        const bf16x4 ov = *reinterpret_cast<const bf16x4*>(
            Opart + ((size_t)(i * 16 + bh) * 2048 + s) * 64 + d4 * 4);
#pragma unroll
        for (int j = 0; j < 4; ++j) o[j] += w * (float)ov[j];
    }
    const float inv = 1.0f / wsum;
    bf16x4 r;
#pragma unroll
    for (int i = 0; i < 4; ++i) r[i] = (bf16_t)(o[i] * inv);
    *reinterpret_cast<bf16x4*>(CTX + ((size_t)b * S + s) * 512 + h * 64 + d4 * 4) = r;
}

// ---------------------------------------------------------------------------
// Kernel 3: output projection via the same GEMM tile. grid 512 x 256 thr.
// ---------------------------------------------------------------------------
__global__ __launch_bounds__(256) void out_proj_kernel(
    const bf16_t* __restrict__ CTX,
    const bf16_t* __restrict__ WoT,
    const float* __restrict__ bo,
    float* __restrict__ out)
{
    __shared__ char lds[2][16384];

    const int mtile = blockIdx.x & 63;      // low bits -> XCD
    const int ntile = blockIdx.x >> 6;
    const int row0 = mtile * 64, n0 = ntile * 64;

    const int lane = threadIdx.x & 63;
    const int g = lane >> 4, c = lane & 15;
    const int wave = threadIdx.x >> 6, wm = wave >> 1, wn = wave & 1;

    const f32x4 zero = {0.f, 0.f, 0.f, 0.f};
    f32x4 acc[2][2] = {{zero, zero}, {zero, zero}};
    gemm_tile(CTX, WoT, row0, n0, &lds[0][0], acc);

#pragma unroll
    for (int mf = 0; mf < 2; ++mf)
#pragma unroll
        for (int nf = 0; nf < 2; ++nf) {
            const int n = n0 + wn * 32 + nf * 16 + c;
            const float bval = bo[n];
            const int rowb = row0 + wm * 32 + mf * 16 + 4 * g;
#pragma unroll
            for (int i = 0; i < 4; ++i)
                out[(size_t)(rowb + i) * 512 + n] = acc[mf][nf][i] + bval;
        }
}

// ---------------------------------------------------------------------------
extern "C" void kernel_launch(void* const* d_in, const int* in_sizes, int n_in,
                              void* d_out, int out_size, void* d_ws, size_t ws_size,
                              hipStream_t stream) {
    const float* query = (const float*)d_in[0];
    const float* key_  = (const float*)d_in[1];
    const float* value = (const float*)d_in[2];
    const float* Wq = (const float*)d_in[3];
    const float* bq = (const float*)d_in[4];
    const float* Wk = (const float*)d_in[5];
    const float* bk = (const float*)d_in[6];
    const float* Wv = (const float*)d_in[7];
    const float* bv = (const float*)d_in[8];
    const float* Wo = (const float*)d_in[9];
    const float* bo = (const float*)d_in[10];

    char* wsb = (char*)d_ws;
    bf16_t* Qw   = (bf16_t*)(wsb);                       // 4 MB
    bf16_t* Kw   = (bf16_t*)(wsb + (4u  << 20));         // 4 MB
    bf16_t* VTw  = (bf16_t*)(wsb + (8u  << 20));         // 4 MB
    bf16_t* CTXb = (bf16_t*)(wsb + (12u << 20));         // 4 MB
    bf16_t* Wtq  = (bf16_t*)(wsb + (16u << 20));         // 512 KB
    bf16_t* Wtk  = Wtq + 8 * 64 * 512;
    bf16_t* Wtv  = Wtk + 8 * 64 * 512;
    bf16_t* WoTw = (bf16_t*)(wsb + (18u << 20));         // 512 KB
    bf16_t* Xq   = (bf16_t*)(wsb + (20u << 20));         // 4 MB
    bf16_t* Xk   = (bf16_t*)(wsb + (24u << 20));         // 4 MB
    bf16_t* Xv   = (bf16_t*)(wsb + (28u << 20));         // 4 MB
    bf16_t* Opart = (bf16_t*)(wsb + (32u << 20));        // SPLIT x 4 MB (bf16)

    const int SPLIT = (ws_size >= (70ull << 20)) ? 4
                    : (ws_size >= (52ull << 20)) ? 2 : 1;

    prep_kernel<<<256, 256, 0, stream>>>(Wq, Wk, Wv, Wo, Wtq, Wtk, Wtv, WoTw);
    xcvt_kernel<<<dim3(1024, 3), 256, 0, stream>>>(query, key_, value, Xq, Xk, Xv);
    qkv_kernel<<<dim3(512, 3), 256, 0, stream>>>(Xq, Xk, Xv,
                                                 Wtq, Wtk, Wtv, bq, bk, bv,
                                                 Qw, Kw, VTw);

    if (SPLIT == 4) {
        float* MLp = (float*)(Opart + 4ull * 16 * 2048 * 64);
        attn_kernel<4><<<1024, 512, 0, stream>>>(Qw, Kw, VTw, CTXb, Opart, MLp);
        combine_kernel<4><<<2048, 256, 0, stream>>>(Opart, MLp, CTXb);
    } else if (SPLIT == 2) {
        float* MLp = (float*)(Opart + 2ull * 16 * 2048 * 64);
        attn_kernel<2><<<512, 512, 0, stream>>>(Qw, Kw, VTw, CTXb, Opart, MLp);
        combine_kernel<2><<<2048, 256, 0, stream>>>(Opart, MLp, CTXb);
    } else {
        attn_kernel<1><<<256, 512, 0, stream>>>(Qw, Kw, VTw, CTXb, nullptr, nullptr);
    }

    out_proj_kernel<<<512, 256, 0, stream>>>(CTXb, WoTw, bo, (float*)d_out);
}